// Round 11
// baseline (286.268 us; speedup 1.0000x reference)
//
#include <hip/hip_runtime.h>
#include <math.h>
#include <stdint.h>

#define H 512
#define W 512
#define NPIX (H * W)          // 262144
#define NB 2
#define NF 180
#define KS 17
#define WSCALE 1024.0f        // exact power of two; cancels in both outputs

// LDS pool (u32): raw 20*48=960; B double buffer 2 phases * 2 chunks * 3072
#define RAW_OFF 0
#define BB_OFF  960
#define BCH_U32 3072          // one K-chunk of B (hi+lo, N=192), 12 KB
#define PH_U32  (2 * BCH_U32) // 2-chunk phase buffer, 24 KB
#define POOL_U32 (960 + 2 * PH_U32)   // 13248 u32 = 53.0 KB -> 3 blocks/CU

typedef _Float16 half8 __attribute__((ext_vector_type(8)));
typedef float floatx16 __attribute__((ext_vector_type(16)));
typedef uint32_t u32x4 __attribute__((ext_vector_type(4)));

union FragU { u32x4 u; half8 h; };

__device__ inline void gl_lds16(const uint32_t* g, uint32_t* l) {
  __builtin_amdgcn_global_load_lds((const __attribute__((address_space(1))) void*)g,
                                   (__attribute__((address_space(3))) void*)l, 16, 0, 0);
}

// ---------------- taps (match numpy float64 _gauss1d) ----------------
__global__ void k_taps(float* __restrict__ taps) {
  if (threadIdx.x == 0 && blockIdx.x == 0) {
    {
      double k[5], s = 0.0;
      for (int i = 0; i < 5; i++) { double xv = (double)(i - 2) / 0.4; k[i] = exp(-0.5 * xv * xv); s += k[i]; }
      for (int i = 0; i < 5; i++) taps[i] = (float)(k[i] / s);
    }
    {
      double k[81], s = 0.0;
      for (int i = 0; i < 81; i++) { double xv = (double)(i - 40) / 10.0; k[i] = exp(-0.5 * xv * xv); s += k[i]; }
      for (int i = 0; i < 81; i++) taps[8 + i] = (float)(k[i] / s);
    }
  }
}

// ---------------- weight repack into MFMA B-fragment order, f16 split ----------------
// Bf (u32): chunk c (19): [c*3072 ..]: hi frags: t*256 + lane*4 + q ; lo at +1536
// B[k][n]: n = t*32 + (lane&31), k = 8*(lane>>5) + j, dword q holds j=2q (lo16), j=2q+1 (hi16)
// chunks: c<17: (ky=c, kx=k); c==17: (ky=k, kx=16); c==18: k==0 -> (ky=16,kx=16)
__global__ void k_repackB(const float* __restrict__ w, uint32_t* __restrict__ Bf) {
  int tid = blockIdx.x * 256 + threadIdx.x;
  if (tid >= 19 * 6 * 64 * 4) return;
  int q = tid & 3;
  int lane = (tid >> 2) & 63;
  int ct = tid >> 8;
  int t = ct % 6, c = ct / 6;
  int n = t * 32 + (lane & 31);
  int hf = lane >> 5;
  uint32_t hv = 0, lv = 0;
  for (int s = 0; s < 2; s++) {
    int j = 2 * q + s;
    int k = hf * 8 + j;   // 0..15
    float val = 0.f;
    if (n < NF) {
      if (c < 17)       val = w[n * 289 + c * 17 + k];
      else if (c == 17) val = w[n * 289 + k * 17 + 16];
      else if (k == 0)  val = w[n * 289 + 16 * 17 + 16];
    }
    val *= WSCALE;
    _Float16 hh = (_Float16)val;
    _Float16 ll = (_Float16)(val - (float)hh);
    hv |= (uint32_t)__builtin_bit_cast(uint16_t, hh) << (16 * s);
    lv |= (uint32_t)__builtin_bit_cast(uint16_t, ll) << (16 * s);
  }
  int base = c * 3072;
  int off = t * 256 + lane * 4 + q;
  Bf[base + off] = hv;
  Bf[base + 1536 + off] = lv;
}

// ---------------- gray ----------------
__global__ void k_gray(const float* __restrict__ x, float* __restrict__ gray) {
  int i = blockIdx.x * blockDim.x + threadIdx.x;
  if (i >= NB * NPIX) return;
  int b = i / NPIX, r = i % NPIX;
  const float* xb = x + (size_t)b * 3 * NPIX;
  gray[i] = 0.2989f * xb[r] + 0.587f * xb[NPIX + r] + 0.114f * xb[2 * NPIX + r];
}

// ---------------- vertical blur, both sigmas fused ----------------
__global__ void k_vblur2(const float* __restrict__ in, float* __restrict__ outA,
                         float* __restrict__ outB, const float* __restrict__ taps) {
  int i = blockIdx.x * blockDim.x + threadIdx.x;
  if (i >= NB * NPIX) return;
  int b = i / NPIX, r = i % NPIX;
  int y = r / W, xx = r % W;
  const float* img = in + (size_t)b * NPIX;
  float a = 0.f;
#pragma unroll
  for (int j = -2; j <= 2; j++) {
    int yy = y + j; yy = yy < 0 ? 0 : (yy > H - 1 ? H - 1 : yy);
    a = fmaf(taps[j + 2], img[yy * W + xx], a);
  }
  float c = 0.f;
  for (int j = -40; j <= 40; j++) {
    int yy = y + j; yy = yy < 0 ? 0 : (yy > H - 1 ? H - 1 : yy);
    c = fmaf(taps[8 + j + 40], img[yy * W + xx], c);
  }
  outA[i] = a;
  outB[i] = c;
}

// ---------------- horizontal blur + DoG + f16-split pack ----------------
__global__ void k_hblur_dog(const float* __restrict__ inA, const float* __restrict__ inB,
                            uint32_t* __restrict__ dogp, const float* __restrict__ taps) {
  int i = blockIdx.x * blockDim.x + threadIdx.x;
  if (i >= NB * NPIX) return;
  int b = i / NPIX, r = i % NPIX;
  int y = r / W, xx = r % W;
  const float* ra = inA + (size_t)b * NPIX + (size_t)y * W;
  const float* rb = inB + (size_t)b * NPIX + (size_t)y * W;
  float a = 0.f;
#pragma unroll
  for (int j = -2; j <= 2; j++) {
    int xc = xx + j; xc = xc < 0 ? 0 : (xc > W - 1 ? W - 1 : xc);
    a = fmaf(taps[j + 2], ra[xc], a);
  }
  float c = 0.f;
  for (int j = -40; j <= 40; j++) {
    int xc = xx + j; xc = xc < 0 ? 0 : (xc > W - 1 ? W - 1 : xc);
    c = fmaf(taps[8 + j + 40], rb[xc], c);
  }
  float d = a - c;
  _Float16 hh = (_Float16)d;
  _Float16 ll = (_Float16)(d - (float)hh);
  dogp[i] = ((uint32_t)__builtin_bit_cast(uint16_t, ll) << 16) |
            (uint32_t)__builtin_bit_cast(uint16_t, hh);
}

// ---------------- main: implicit-GEMM MFMA conv ----------------
// grid 4096 (XCD-swizzled, y-major); block 256 thr = 4 waves; wave w:
//   rp = w>>1 (row pair: rows 2rp, 2rp+1, A-frag ROLLS), g = w&1 (n-group: 96 filters)
// wave tile: M = 2 rows x 32 cols (2 m-tiles), N = 96 (3 n-tiles), acc = 96 VGPR.
// 53 KB LDS -> 3 blocks/CU -> 3 waves/SIMD anti-phased.
__launch_bounds__(256, 3)
__global__ void k_conv(const uint32_t* __restrict__ dogp,
                       const uint32_t* __restrict__ Bf,
                       const float* __restrict__ bins,
                       float* __restrict__ out) {
  __shared__ uint32_t pool[POOL_U32];

  const int nid = blockIdx.x;
  const int bid = (nid & 7) * 512 + (nid >> 3);   // bijective XCD swizzle (4096 = 8*512)
  const int bz = bid >> 11;          // batch (0..1)
  const int rem = bid & 2047;
  const int bx = rem >> 7;           // 0..15
  const int by = rem & 127;          // 0..127, consecutive within an XCD chunk (A-row reuse)

  const int b  = bz;
  const int y0 = by * 4;
  const int x0 = bx * 32;
  const int tid = threadIdx.x;
  const int lane = tid & 63;
  const int w  = __builtin_amdgcn_readfirstlane(tid >> 6);  // 0..3
  const int rp = w >> 1;          // row pair (0..1): rows y0+2rp, y0+2rp+1
  const int g  = w & 1;           // n-group (filters g*96 .. g*96+95)
  const int nl = lane & 31;
  const int half = lane >> 5;

  // ---- stage raw rows y0-8 .. y0+11 (20), cols x0-8 .. x0+39 (48, zero-padded) ----
  const uint32_t* dgb = dogp + (size_t)b * NPIX;
  for (int i = tid; i < 20 * 48; i += 256) {
    int ry = i / 48, rx = i % 48;
    int gy = y0 + ry - 8, gx = x0 + rx - 8;
    uint32_t v = 0;
    if (gy >= 0 && gy < H && gx >= 0 && gx < W) v = dgb[gy * W + gx];
    pool[RAW_OFF + i] = v;
  }
  // ---- stage B chunks 0,1 into phase buffer 0 ----
  {
    const uint32_t* src = Bf + (size_t)tid * 4;
    uint32_t* dst = &pool[BB_OFF + tid * 4];
#pragma unroll
    for (int i = 0; i < 6; i++) gl_lds16(src + i * 1024, dst + i * 1024);
  }
  asm volatile("s_waitcnt vmcnt(0)" ::: "memory");
  __syncthreads();

  floatx16 acc[2][3];
#pragma unroll
  for (int mt = 0; mt < 2; mt++)
#pragma unroll
    for (int t = 0; t < 3; t++)
#pragma unroll
      for (int q = 0; q < 16; q++) acc[mt][t][q] = 0.f;

  const int abase = nl + half * 8;

  // build A row fragment (hi/lo) for raw row tr
  auto buildRow = [&](int tr, FragU& fh, FragU& fl) {
    const uint32_t* rpt = &pool[RAW_OFF + tr * 48 + abase];
    uint32_t d[8];
#pragma unroll
    for (int j = 0; j < 8; j++) d[j] = rpt[j];
#pragma unroll
    for (int q = 0; q < 4; q++) {
      fh.u[q] = __builtin_amdgcn_perm(d[2 * q + 1], d[2 * q], 0x05040100u);
      fl.u[q] = __builtin_amdgcn_perm(d[2 * q + 1], d[2 * q], 0x07060302u);
    }
  };
  // build A strip fragment (kx=16 col) for tail chunk c (17/18), m-tile row base rb
  auto buildStrip = [&](int c, int rb, FragU& fh, FragU& fl) {
    int kyb = (c - 17) * 16 + half * 8;
    uint32_t d[8];
#pragma unroll
    for (int j = 0; j < 8; j++) {
      int ky = kyb + j; if (ky > 16) ky = 16;   // clamped reads killed by B=0
      d[j] = pool[RAW_OFF + (rb + ky) * 48 + nl + 16];
    }
#pragma unroll
    for (int q = 0; q < 4; q++) {
      fh.u[q] = __builtin_amdgcn_perm(d[2 * q + 1], d[2 * q], 0x05040100u);
      fl.u[q] = __builtin_amdgcn_perm(d[2 * q + 1], d[2 * q], 0x07060302u);
    }
  };
  // one K-chunk: read this wave's 3 n-tiles (hi+lo), 18 MFMAs
  auto doChunk = [&](int off, FragU& a0h, FragU& a0l, FragU& a1h, FragU& a1l) {
    FragU bh[3], bl[3];
#pragma unroll
    for (int t = 0; t < 3; t++) {
      bh[t].u = *(const u32x4*)&pool[off + (3 * g + t) * 256 + lane * 4];
      bl[t].u = *(const u32x4*)&pool[off + 1536 + (3 * g + t) * 256 + lane * 4];
    }
    __builtin_amdgcn_s_setprio(1);
#pragma unroll
    for (int t = 0; t < 3; t++) {
      acc[0][t] = __builtin_amdgcn_mfma_f32_32x32x16_f16(a0h.h, bh[t].h, acc[0][t], 0, 0, 0);
      acc[1][t] = __builtin_amdgcn_mfma_f32_32x32x16_f16(a1h.h, bh[t].h, acc[1][t], 0, 0, 0);
    }
#pragma unroll
    for (int t = 0; t < 3; t++) {
      acc[0][t] = __builtin_amdgcn_mfma_f32_32x32x16_f16(a0l.h, bh[t].h, acc[0][t], 0, 0, 0);
      acc[1][t] = __builtin_amdgcn_mfma_f32_32x32x16_f16(a1l.h, bh[t].h, acc[1][t], 0, 0, 0);
    }
#pragma unroll
    for (int t = 0; t < 3; t++) {
      acc[0][t] = __builtin_amdgcn_mfma_f32_32x32x16_f16(a0h.h, bl[t].h, acc[0][t], 0, 0, 0);
      acc[1][t] = __builtin_amdgcn_mfma_f32_32x32x16_f16(a1h.h, bl[t].h, acc[1][t], 0, 0, 0);
    }
    __builtin_amdgcn_s_setprio(0);
  };

  FragU a0h, a0l, a1h, a1l;
  buildRow(2 * rp, a0h, a0l);   // chunk 0, m-tile 0 (rolls forward)

  int buf = 0;
  for (int p = 0; p < 8; p++) {          // chunks 2p, 2p+1 (c <= 15, row-type)
    // stage chunks 2p+2, 2p+3 into the other phase buffer
    {
      const uint32_t* src = Bf + (size_t)(2 * p + 2) * BCH_U32 + (size_t)tid * 4;
      uint32_t* dst = &pool[BB_OFF + (buf ^ 1) * PH_U32 + tid * 4];
#pragma unroll
      for (int i = 0; i < 6; i++) gl_lds16(src + i * 1024, dst + i * 1024);
    }
    // chunk c0 = 2p
    buildRow(2 * rp + 1 + 2 * p, a1h, a1l);
    doChunk(BB_OFF + buf * PH_U32, a0h, a0l, a1h, a1l);
    a0h = a1h; a0l = a1l;
    // chunk c1 = 2p+1
    buildRow(2 * rp + 2 + 2 * p, a1h, a1l);
    doChunk(BB_OFF + buf * PH_U32 + BCH_U32, a0h, a0l, a1h, a1l);
    a0h = a1h; a0l = a1l;

    asm volatile("s_waitcnt vmcnt(0)" ::: "memory");
    __syncthreads();
    buf ^= 1;
  }

  // phase 8: chunks 16 (row-type, rolled) and 17 (strip); stage chunk 18
  {
    const uint32_t* src = Bf + (size_t)18 * BCH_U32 + (size_t)tid * 4;
    uint32_t* dst = &pool[BB_OFF + (buf ^ 1) * PH_U32 + tid * 4];
#pragma unroll
    for (int i = 0; i < 3; i++) gl_lds16(src + i * 1024, dst + i * 1024);

    buildRow(2 * rp + 17, a1h, a1l);                // c=16, m-tile 1
    doChunk(BB_OFF + buf * PH_U32, a0h, a0l, a1h, a1l);

    FragU s0h, s0l, s1h, s1l;
    buildStrip(17, 2 * rp, s0h, s0l);
    buildStrip(17, 2 * rp + 1, s1h, s1l);
    doChunk(BB_OFF + buf * PH_U32 + BCH_U32, s0h, s0l, s1h, s1l);

    asm volatile("s_waitcnt vmcnt(0)" ::: "memory");
    __syncthreads();
    buf ^= 1;
  }
  // phase 9: chunk 18 (strip), no staging
  {
    FragU s0h, s0l, s1h, s1l;
    buildStrip(18, 2 * rp, s0h, s0l);
    buildStrip(18, 2 * rp + 1, s1h, s1l);
    doChunk(BB_OFF + buf * PH_U32, s0h, s0l, s1h, s1l);
  }
  __syncthreads();   // raw region dead from here; safe to alias

  // ---- epilogue: cross-wave combine of the two n-groups via LDS partials ----
  float* pm = (float*)&pool[0];      // [rp][mt][g][32]  (256)
  int*   pn = (int*)&pool[256];      // (256)
  float* pS = (float*)&pool[512];    // (256)
  float* pc = (float*)&pool[768];    // (256)
  int*   fn = (int*)&pool[1024];     // [rp][mt][32]     (128)
  float* fS = (float*)&pool[1152];   // (128)

  const float PI_F = 3.14159265358979323846f;
  float bn[3];
#pragma unroll
  for (int t = 0; t < 3; t++) {
    int n = g * 96 + t * 32 + nl;
    bn[t] = (n < NF) ? bins[n] : 0.f;
  }

  // stage 1: per-wave partial argmax/sum over its 96 filters
#pragma unroll
  for (int mt = 0; mt < 2; mt++) {
#pragma unroll
    for (int q = 0; q < 16; q++) {
      float m = -1.f, S = 0.f;
      int bt = 0;
#pragma unroll
      for (int t = 0; t < 3; t++) {
        float v = fabsf(acc[mt][t][q]);
        S += v;
        if (v > m) { m = v; bt = t; }
      }
      int n = g * 96 + bt * 32 + nl;
#pragma unroll
      for (int msk = 1; msk < 32; msk <<= 1) {
        float vo = __shfl_xor(m, msk);
        int   no = __shfl_xor(n, msk);
        float So = __shfl_xor(S, msk);
        bool take = (vo > m) || (vo == m && no < n);
        m = take ? vo : m;
        n = take ? no : n;
        S += So;
      }
      if (nl == 0) {
        int px = (q & 3) + 8 * (q >> 2) + 4 * half;
        int o = ((rp * 2 + mt) * 2 + g) * 32 + px;
        pm[o] = m; pn[o] = n; pS[o] = S;
      }
    }
  }
  __syncthreads();

  // stage 2: g==0 waves combine n-groups (lane -> mt,px), write orientation
  if (g == 0) {
    int mt = lane >> 5, px = lane & 31;
    int o0 = ((rp * 2 + mt) * 2 + 0) * 32 + px;
    int o1 = ((rp * 2 + mt) * 2 + 1) * 32 + px;
    float m0 = pm[o0], m1 = pm[o1];
    int n = (m1 > m0) ? pn[o1] : pn[o0];   // strict > keeps smaller index on tie
    float S = pS[o0] + pS[o1];
    int fo = (rp * 2 + mt) * 32 + px;
    fn[fo] = n; fS[fo] = S;
    float om = (float)n / 180.0f * 255.0f;
    out[(size_t)b * NPIX + (size_t)(y0 + 2 * rp + mt) * W + x0 + px] = om;
  }
  __syncthreads();

  // stage 3: per-wave partial confidence with the final winner
#pragma unroll
  for (int mt = 0; mt < 2; mt++) {
#pragma unroll
    for (int q = 0; q < 16; q++) {
      int px = (q & 3) + 8 * (q >> 2) + 4 * half;
      int nwin = fn[(rp * 2 + mt) * 32 + px];
      float om = (float)nwin / 180.0f * 255.0f;
      float rad = om / 180.0f * PI_F;
      float C = 0.f;
#pragma unroll
      for (int t = 0; t < 3; t++) {
        float dd = rad - bn[t];
        float d0 = fabsf(dd);
        float d1 = fabsf(dd - PI_F);
        float d2 = fabsf(dd + PI_F);
        float d = fminf(d0, fminf(d1, d2));
        C = fmaf(d * d, fabsf(acc[mt][t][q]), C);
      }
#pragma unroll
      for (int msk = 1; msk < 32; msk <<= 1) C += __shfl_xor(C, msk);
      if (nl == 0) pc[((rp * 2 + mt) * 2 + g) * 32 + px] = C;
    }
  }
  __syncthreads();

  // stage 4: g==0 waves finalize confidence
  if (g == 0) {
    int mt = lane >> 5, px = lane & 31;
    float C = pc[((rp * 2 + mt) * 2 + 0) * 32 + px] + pc[((rp * 2 + mt) * 2 + 1) * 32 + px];
    int fo = (rp * 2 + mt) * 32 + px;
    out[(size_t)NB * NPIX + (size_t)b * NPIX + (size_t)(y0 + 2 * rp + mt) * W + x0 + px]
        = C / fS[fo];
  }
}

extern "C" void kernel_launch(void* const* d_in, const int* in_sizes, int n_in,
                              void* d_out, int out_size, void* d_ws, size_t ws_size,
                              hipStream_t stream) {
  const float* x = (const float*)d_in[0];      // [2,3,512,512]
  const float* wts = (const float*)d_in[1];    // [180,1,17,17]
  const float* bins = (const float*)d_in[2];   // [180]
  float* out = (float*)d_out;

  float* ws = (float*)d_ws;
  float* gray = ws;                                 // 524288 f32
  float* tmpA = ws + (size_t)NB * NPIX;             // 524288 f32
  float* tmpB = tmpA + (size_t)NB * NPIX;           // 524288 f32
  uint32_t* dogp = (uint32_t*)(tmpB + (size_t)NB * NPIX);  // 524288 u32
  float* taps = (float*)(dogp + (size_t)NB * NPIX); // 128 f32
  uint32_t* Bf = (uint32_t*)(taps + 128);           // 19*3072 u32

  k_taps<<<1, 64, 0, stream>>>(taps);
  k_repackB<<<114, 256, 0, stream>>>(wts, Bf);

  int n = NB * NPIX;
  int blk = 256, grd = (n + blk - 1) / blk;
  k_gray<<<grd, blk, 0, stream>>>(x, gray);
  k_vblur2<<<grd, blk, 0, stream>>>(gray, tmpA, tmpB, taps);
  k_hblur_dog<<<grd, blk, 0, stream>>>(tmpA, tmpB, dogp, taps);

  k_conv<<<4096, 256, 0, stream>>>(dogp, Bf, bins, out);
}

// Round 13
// 213.190 us; speedup vs baseline: 1.3428x; 1.3428x over previous
//
#include <hip/hip_runtime.h>
#include <math.h>
#include <stdint.h>

#define H 512
#define W 512
#define NPIX (H * W)          // 262144
#define NB 2
#define NF 180
#define KS 17
#define WSCALE 1024.0f        // exact power of two; cancels in both outputs

// LDS pool (u32): raw rows 20*80=1600; B double buffer 2 phases * 2 chunks * 3072
#define RAW_OFF 0
#define BB_OFF  1600
#define BCH_U32 3072          // one K-chunk of weights (hi+lo, 192 filters), 12 KB
#define PH_U32  (2 * BCH_U32) // 2-chunk phase buffer, 24 KB
#define POOL_U32 (1600 + 2 * PH_U32)   // 13888 u32 = 55.5 KB -> 2 blocks/CU

typedef _Float16 half8 __attribute__((ext_vector_type(8)));
typedef float floatx16 __attribute__((ext_vector_type(16)));
typedef uint32_t u32x4 __attribute__((ext_vector_type(4)));

union FragU { u32x4 u; half8 h; };

__device__ inline void gl_lds16(const uint32_t* g, uint32_t* l) {
  __builtin_amdgcn_global_load_lds((const __attribute__((address_space(1))) void*)g,
                                   (__attribute__((address_space(3))) void*)l, 16, 0, 0);
}

// ---------------- taps (match numpy float64 _gauss1d) ----------------
__global__ void k_taps(float* __restrict__ taps) {
  if (threadIdx.x == 0 && blockIdx.x == 0) {
    {
      double k[5], s = 0.0;
      for (int i = 0; i < 5; i++) { double xv = (double)(i - 2) / 0.4; k[i] = exp(-0.5 * xv * xv); s += k[i]; }
      for (int i = 0; i < 5; i++) taps[i] = (float)(k[i] / s);
    }
    {
      double k[81], s = 0.0;
      for (int i = 0; i < 81; i++) { double xv = (double)(i - 40) / 10.0; k[i] = exp(-0.5 * xv * xv); s += k[i]; }
      for (int i = 0; i < 81; i++) taps[8 + i] = (float)(k[i] / s);
    }
  }
}

// ---------------- weight repack into MFMA fragment order, f16 split ----------------
// Bf (u32): chunk c (19): [c*3072 ..]: hi frags: t*256 + lane*4 + q ; lo at +1536
// W[m][k]: m = t*32 + (lane&31) (filter), k = 8*(lane>>5) + j, dword q: j=2q lo16, j=2q+1 hi16
// chunks: c<17: (ky=c, kx=k); c==17: (ky=k, kx=16); c==18: k==0 -> (ky=16,kx=16)
__global__ void k_repackB(const float* __restrict__ w, uint32_t* __restrict__ Bf) {
  int tid = blockIdx.x * 256 + threadIdx.x;
  if (tid >= 19 * 6 * 64 * 4) return;
  int q = tid & 3;
  int lane = (tid >> 2) & 63;
  int ct = tid >> 8;
  int t = ct % 6, c = ct / 6;
  int n = t * 32 + (lane & 31);
  int hf = lane >> 5;
  uint32_t hv = 0, lv = 0;
  for (int s = 0; s < 2; s++) {
    int j = 2 * q + s;
    int k = hf * 8 + j;   // 0..15
    float val = 0.f;
    if (n < NF) {
      if (c < 17)       val = w[n * 289 + c * 17 + k];
      else if (c == 17) val = w[n * 289 + k * 17 + 16];
      else if (k == 0)  val = w[n * 289 + 16 * 17 + 16];
    }
    val *= WSCALE;
    _Float16 hh = (_Float16)val;
    _Float16 ll = (_Float16)(val - (float)hh);
    hv |= (uint32_t)__builtin_bit_cast(uint16_t, hh) << (16 * s);
    lv |= (uint32_t)__builtin_bit_cast(uint16_t, ll) << (16 * s);
  }
  int base = c * 3072;
  int off = t * 256 + lane * 4 + q;
  Bf[base + off] = hv;
  Bf[base + 1536 + off] = lv;
}

// ---------------- gray ----------------
__global__ void k_gray(const float* __restrict__ x, float* __restrict__ gray) {
  int i = blockIdx.x * blockDim.x + threadIdx.x;
  if (i >= NB * NPIX) return;
  int b = i / NPIX, r = i % NPIX;
  const float* xb = x + (size_t)b * 3 * NPIX;
  gray[i] = 0.2989f * xb[r] + 0.587f * xb[NPIX + r] + 0.114f * xb[2 * NPIX + r];
}

// ---------------- vertical blur, both sigmas fused ----------------
__global__ void k_vblur2(const float* __restrict__ in, float* __restrict__ outA,
                         float* __restrict__ outB, const float* __restrict__ taps) {
  int i = blockIdx.x * blockDim.x + threadIdx.x;
  if (i >= NB * NPIX) return;
  int b = i / NPIX, r = i % NPIX;
  int y = r / W, xx = r % W;
  const float* img = in + (size_t)b * NPIX;
  float a = 0.f;
#pragma unroll
  for (int j = -2; j <= 2; j++) {
    int yy = y + j; yy = yy < 0 ? 0 : (yy > H - 1 ? H - 1 : yy);
    a = fmaf(taps[j + 2], img[yy * W + xx], a);
  }
  float c = 0.f;
  for (int j = -40; j <= 40; j++) {
    int yy = y + j; yy = yy < 0 ? 0 : (yy > H - 1 ? H - 1 : yy);
    c = fmaf(taps[8 + j + 40], img[yy * W + xx], c);
  }
  outA[i] = a;
  outB[i] = c;
}

// ---------------- horizontal blur + DoG + f16-split pack ----------------
__global__ void k_hblur_dog(const float* __restrict__ inA, const float* __restrict__ inB,
                            uint32_t* __restrict__ dogp, const float* __restrict__ taps) {
  int i = blockIdx.x * blockDim.x + threadIdx.x;
  if (i >= NB * NPIX) return;
  int b = i / NPIX, r = i % NPIX;
  int y = r / W, xx = r % W;
  const float* ra = inA + (size_t)b * NPIX + (size_t)y * W;
  const float* rb = inB + (size_t)b * NPIX + (size_t)y * W;
  float a = 0.f;
#pragma unroll
  for (int j = -2; j <= 2; j++) {
    int xc = xx + j; xc = xc < 0 ? 0 : (xc > W - 1 ? W - 1 : xc);
    a = fmaf(taps[j + 2], ra[xc], a);
  }
  float c = 0.f;
  for (int j = -40; j <= 40; j++) {
    int xc = xx + j; xc = xc < 0 ? 0 : (xc > W - 1 ? W - 1 : xc);
    c = fmaf(taps[8 + j + 40], rb[xc], c);
  }
  float d = a - c;
  _Float16 hh = (_Float16)d;
  _Float16 ll = (_Float16)(d - (float)hh);
  dogp[i] = ((uint32_t)__builtin_bit_cast(uint16_t, ll) << 16) |
            (uint32_t)__builtin_bit_cast(uint16_t, hh);
}

// ---------------- main: TRANSPOSED implicit-GEMM MFMA conv ----------------
// GEMM: A = weights (M=192 filters), B = data (N=pixels). C: col=lane&31=pixel,
// row=filter -> each lane holds 96 filters of ONE pixel in registers; the
// per-pixel argmax/sum/conf reduction is lane-local + 4 shfl_xor(32) merges.
// block: 256 thr = 4 waves; wave w: rp=w>>1 (row pair), ch=w&1 (col half)
// wave tile: 2 data rows x 32 cols (data frags ROLL across chunks), 192 filters.
__launch_bounds__(256, 2)
__global__ void k_conv(const uint32_t* __restrict__ dogp,
                       const uint32_t* __restrict__ Bf,
                       const float* __restrict__ bins,
                       float* __restrict__ out) {
  __shared__ uint32_t pool[POOL_U32];

  const int b  = blockIdx.z;
  const int y0 = blockIdx.y * 4;
  const int x0 = blockIdx.x * 64;
  const int tid = threadIdx.x;
  const int lane = tid & 63;
  const int w  = __builtin_amdgcn_readfirstlane(tid >> 6);  // 0..3
  const int rp2 = (w >> 1) * 2;   // 0 or 2: wave's row-pair base
  const int ch  = w & 1;          // col half (0: cols 0..31, 1: 32..63)
  const int nl = lane & 31;
  const int half = lane >> 5;

  // ---- stage raw rows y0-8 .. y0+11 (20), cols x0-8 .. x0+71 (zero-padded) ----
  const uint32_t* dgb = dogp + (size_t)b * NPIX;
  for (int i = tid; i < 20 * 80; i += 256) {
    int ry = i / 80, rx = i % 80;
    int gy = y0 + ry - 8, gx = x0 + rx - 8;
    uint32_t v = 0;
    if (gy >= 0 && gy < H && gx >= 0 && gx < W) v = dgb[gy * W + gx];
    pool[RAW_OFF + i] = v;
  }
  // ---- stage weight chunks 0,1 into phase buffer 0 ----
  {
    const uint32_t* src = Bf + (size_t)tid * 4;
    uint32_t* dst = &pool[BB_OFF + tid * 4];
#pragma unroll
    for (int i = 0; i < 6; i++) gl_lds16(src + i * 1024, dst + i * 1024);
  }
  asm volatile("s_waitcnt vmcnt(0)" ::: "memory");
  __syncthreads();

  floatx16 acc[2][6];   // [data row d][filter tile t]
#pragma unroll
  for (int d = 0; d < 2; d++)
#pragma unroll
    for (int t = 0; t < 6; t++)
#pragma unroll
      for (int q = 0; q < 16; q++) acc[d][t][q] = 0.f;

  const int abase = ch * 32 + nl + half * 8;

  // build data fragment (hi/lo) for tile row tr (B-operand; layout same as before)
  auto buildRow = [&](int tr, FragU& fh, FragU& fl) {
    const uint32_t* rp = &pool[RAW_OFF + tr * 80 + abase];
    uint32_t d[8];
#pragma unroll
    for (int j = 0; j < 8; j++) d[j] = rp[j];
#pragma unroll
    for (int q = 0; q < 4; q++) {
      fh.u[q] = __builtin_amdgcn_perm(d[2 * q + 1], d[2 * q], 0x05040100u);
      fl.u[q] = __builtin_amdgcn_perm(d[2 * q + 1], d[2 * q], 0x07060302u);
    }
  };
  // build data strip fragment for tail chunk c (17/18), data row base rb
  auto buildStrip = [&](int c, int rb, FragU& fh, FragU& fl) {
    int kyb = (c - 17) * 16 + half * 8;
    uint32_t d[8];
#pragma unroll
    for (int j = 0; j < 8; j++) {
      int ky = kyb + j; if (ky > 16) ky = 16;   // clamped reads killed by W=0
      d[j] = pool[RAW_OFF + (rb + ky) * 80 + ch * 32 + nl + 16];
    }
#pragma unroll
    for (int q = 0; q < 4; q++) {
      fh.u[q] = __builtin_amdgcn_perm(d[2 * q + 1], d[2 * q], 0x05040100u);
      fl.u[q] = __builtin_amdgcn_perm(d[2 * q + 1], d[2 * q], 0x07060302u);
    }
  };
  auto readW = [&](int off, FragU* wh, FragU* wl) {
#pragma unroll
    for (int t = 0; t < 6; t++) {
      wh[t].u = *(const u32x4*)&pool[off + t * 256 + lane * 4];
      wl[t].u = *(const u32x4*)&pool[off + 1536 + t * 256 + lane * 4];
    }
  };
  // 3-term split, same product set & order as before: Dh*Wh, Dl*Wh, Dh*Wl
  auto mfmaChunk = [&](FragU& d0h, FragU& d0l, FragU& d1h, FragU& d1l,
                       FragU* wh, FragU* wl) {
#pragma unroll
    for (int t = 0; t < 6; t++) {
      acc[0][t] = __builtin_amdgcn_mfma_f32_32x32x16_f16(wh[t].h, d0h.h, acc[0][t], 0, 0, 0);
      acc[1][t] = __builtin_amdgcn_mfma_f32_32x32x16_f16(wh[t].h, d1h.h, acc[1][t], 0, 0, 0);
    }
#pragma unroll
    for (int t = 0; t < 6; t++) {
      acc[0][t] = __builtin_amdgcn_mfma_f32_32x32x16_f16(wh[t].h, d0l.h, acc[0][t], 0, 0, 0);
      acc[1][t] = __builtin_amdgcn_mfma_f32_32x32x16_f16(wh[t].h, d1l.h, acc[1][t], 0, 0, 0);
    }
#pragma unroll
    for (int t = 0; t < 6; t++) {
      acc[0][t] = __builtin_amdgcn_mfma_f32_32x32x16_f16(wl[t].h, d0h.h, acc[0][t], 0, 0, 0);
      acc[1][t] = __builtin_amdgcn_mfma_f32_32x32x16_f16(wl[t].h, d1h.h, acc[1][t], 0, 0, 0);
    }
  };

  FragU a0h, a0l, a1h, a1l;
  buildRow(rp2, a0h, a0l);   // chunk 0, data row 0 (rolls forward)

  int buf = 0;
  for (int p = 0; p < 8; p++) {          // chunks 2p, 2p+1 (c <= 15, row-type)
    {
      const uint32_t* src = Bf + (size_t)(2 * p + 2) * BCH_U32 + (size_t)tid * 4;
      uint32_t* dst = &pool[BB_OFF + (buf ^ 1) * PH_U32 + tid * 4];
#pragma unroll
      for (int i = 0; i < 6; i++) gl_lds16(src + i * 1024, dst + i * 1024);
    }
    FragU wh[6], wl[6];
    // chunk c0 = 2p
    buildRow(rp2 + 1 + 2 * p, a1h, a1l);
    readW(BB_OFF + buf * PH_U32, wh, wl);
    mfmaChunk(a0h, a0l, a1h, a1l, wh, wl);
    a0h = a1h; a0l = a1l;
    // chunk c1 = 2p+1
    buildRow(rp2 + 2 + 2 * p, a1h, a1l);
    readW(BB_OFF + buf * PH_U32 + BCH_U32, wh, wl);
    mfmaChunk(a0h, a0l, a1h, a1l, wh, wl);
    a0h = a1h; a0l = a1l;

    asm volatile("s_waitcnt vmcnt(0)" ::: "memory");
    __syncthreads();
    buf ^= 1;
  }

  // phase 8: chunks 16 (row-type, rolled) and 17 (strip); stage chunk 18
  {
    const uint32_t* src = Bf + (size_t)18 * BCH_U32 + (size_t)tid * 4;
    uint32_t* dst = &pool[BB_OFF + (buf ^ 1) * PH_U32 + tid * 4];
#pragma unroll
    for (int i = 0; i < 3; i++) gl_lds16(src + i * 1024, dst + i * 1024);

    FragU wh[6], wl[6];
    buildRow(rp2 + 17, a1h, a1l);                   // c=16, data row 1
    readW(BB_OFF + buf * PH_U32, wh, wl);
    mfmaChunk(a0h, a0l, a1h, a1l, wh, wl);

    FragU s0h, s0l, s1h, s1l;
    buildStrip(17, rp2, s0h, s0l);
    buildStrip(17, rp2 + 1, s1h, s1l);
    readW(BB_OFF + buf * PH_U32 + BCH_U32, wh, wl);
    mfmaChunk(s0h, s0l, s1h, s1l, wh, wl);

    asm volatile("s_waitcnt vmcnt(0)" ::: "memory");
    __syncthreads();
    buf ^= 1;
  }
  // phase 9: chunk 18 (strip), no staging, no barrier
  {
    FragU wh[6], wl[6];
    FragU s0h, s0l, s1h, s1l;
    buildStrip(18, rp2, s0h, s0l);
    buildStrip(18, rp2 + 1, s1h, s1l);
    readW(BB_OFF + buf * PH_U32, wh, wl);
    mfmaChunk(s0h, s0l, s1h, s1l, wh, wl);
  }

  // ---- lane-local epilogue: per lane = 1 pixel x 96 filters (per d) ----
  // filter index for (t,q): n = 32t + (q&3) + 8*(q>>2) + 4*half  (increasing in t,q)
  const float PI_F = 3.14159265358979323846f;
  const float INV_PI = 0.31830988618379067154f;
  const double STEPD = 3.14159265358979323846 * 179.0 / 180.0 / 179.0;
  const float stepf = (float)STEPD;
  const float hbase = (4.0f * (float)half) * stepf;   // bin offset for this half

#pragma unroll
  for (int d = 0; d < 2; d++) {
    // exact local argmax (first-max-wins: n strictly increasing) + sum
    float m = -1.f; int n = 0; float S0 = 0.f, S1 = 0.f;
#pragma unroll
    for (int t = 0; t < 6; t++) {
#pragma unroll
      for (int q = 0; q < 16; q++) {
        float v = fabsf(acc[d][t][q]);
        if (q & 1) S1 += v; else S0 += v;
        int nf = 32 * t + (q & 3) + 8 * (q >> 2) + 4 * half;
        if (v > m) { m = v; n = nf; }
      }
    }
    float S = S0 + S1;
    // merge the two halves (lanes p <-> p+32 hold complementary filter sets)
    {
      float mo = __shfl_xor(m, 32);
      int   no = __shfl_xor(n, 32);
      float So = __shfl_xor(S, 32);
      bool take = (mo > m) || (mo == m && no < n);
      if (take) { m = mo; n = no; }
      S += So;
    }
    float om  = (float)n / 180.0f * 255.0f;
    float rad = om / 180.0f * PI_F;
    float ddc = rad - hbase;
    // confidence: dist = dd - pi*rndne(dd/pi) == min over {dd, dd-pi, dd+pi}
    float C0 = 0.f, C1 = 0.f;
#pragma unroll
    for (int t = 0; t < 6; t++) {
#pragma unroll
      for (int q = 0; q < 16; q++) {
        const float K = (float)((double)(32 * t + (q & 3) + 8 * (q >> 2)) * STEPD);
        float dd = ddc - K;
        float r = rintf(dd * INV_PI);
        float dist = fmaf(-PI_F, r, dd);
        float w2 = dist * dist;
        if (q & 1) C1 = fmaf(w2, fabsf(acc[d][t][q]), C1);
        else       C0 = fmaf(w2, fabsf(acc[d][t][q]), C0);
      }
    }
    float C = C0 + C1;
    C += __shfl_xor(C, 32);
    if (half == 0) {
      int y = y0 + rp2 + d;
      int x = x0 + ch * 32 + nl;
      out[(size_t)b * NPIX + (size_t)y * W + x] = om;
      out[(size_t)NB * NPIX + (size_t)b * NPIX + (size_t)y * W + x] = C / S;
    }
  }
}

extern "C" void kernel_launch(void* const* d_in, const int* in_sizes, int n_in,
                              void* d_out, int out_size, void* d_ws, size_t ws_size,
                              hipStream_t stream) {
  const float* x = (const float*)d_in[0];      // [2,3,512,512]
  const float* wts = (const float*)d_in[1];    // [180,1,17,17]
  const float* bins = (const float*)d_in[2];   // [180]
  float* out = (float*)d_out;

  float* ws = (float*)d_ws;
  float* gray = ws;                                 // 524288 f32
  float* tmpA = ws + (size_t)NB * NPIX;             // 524288 f32
  float* tmpB = tmpA + (size_t)NB * NPIX;           // 524288 f32
  uint32_t* dogp = (uint32_t*)(tmpB + (size_t)NB * NPIX);  // 524288 u32
  float* taps = (float*)(dogp + (size_t)NB * NPIX); // 128 f32
  uint32_t* Bf = (uint32_t*)(taps + 128);           // 19*3072 u32

  k_taps<<<1, 64, 0, stream>>>(taps);
  k_repackB<<<114, 256, 0, stream>>>(wts, Bf);

  int n = NB * NPIX;
  int blk = 256, grd = (n + blk - 1) / blk;
  k_gray<<<grd, blk, 0, stream>>>(x, gray);
  k_vblur2<<<grd, blk, 0, stream>>>(gray, tmpA, tmpB, taps);
  k_hblur_dog<<<grd, blk, 0, stream>>>(tmpA, tmpB, dogp, taps);

  dim3 g(W / 64, H / 4, NB);
  k_conv<<<g, 256, 0, stream>>>(dogp, Bf, bins, out);
}

// Round 14
// 206.892 us; speedup vs baseline: 1.3837x; 1.0304x over previous
//
#include <hip/hip_runtime.h>
#include <math.h>
#include <stdint.h>

#define H 512
#define W 512
#define NPIX (H * W)          // 262144
#define NB 2
#define NF 180
#define KS 17
#define WSCALE 1024.0f        // exact power of two; cancels in both outputs

// LDS pool (u32): raw rows 20*80=1600; B double buffer 2 phases * 2 chunks * 3072
#define RAW_OFF 0
#define BB_OFF  1600
#define BCH_U32 3072          // one K-chunk of weights (hi+lo, 192 filters), 12 KB
#define PH_U32  (2 * BCH_U32) // 2-chunk phase buffer, 24 KB
#define POOL_U32 (1600 + 2 * PH_U32)   // 13888 u32 = 55.5 KB -> 2 blocks/CU

typedef _Float16 half8 __attribute__((ext_vector_type(8)));
typedef float floatx16 __attribute__((ext_vector_type(16)));
typedef uint32_t u32x4 __attribute__((ext_vector_type(4)));

union FragU { u32x4 u; half8 h; };

__device__ inline void gl_lds16(const uint32_t* g, uint32_t* l) {
  __builtin_amdgcn_global_load_lds((const __attribute__((address_space(1))) void*)g,
                                   (__attribute__((address_space(3))) void*)l, 16, 0, 0);
}

// ---------------- taps (match numpy float64 _gauss1d) ----------------
__global__ void k_taps(float* __restrict__ taps) {
  if (threadIdx.x == 0 && blockIdx.x == 0) {
    {
      double k[5], s = 0.0;
      for (int i = 0; i < 5; i++) { double xv = (double)(i - 2) / 0.4; k[i] = exp(-0.5 * xv * xv); s += k[i]; }
      for (int i = 0; i < 5; i++) taps[i] = (float)(k[i] / s);
    }
    {
      double k[81], s = 0.0;
      for (int i = 0; i < 81; i++) { double xv = (double)(i - 40) / 10.0; k[i] = exp(-0.5 * xv * xv); s += k[i]; }
      for (int i = 0; i < 81; i++) taps[8 + i] = (float)(k[i] / s);
    }
  }
}

// ---------------- weight repack into MFMA fragment order, f16 split ----------------
// Bf (u32): chunk c (19): [c*3072 ..]: hi frags: t*256 + lane*4 + q ; lo at +1536
// W[m][k]: m = t*32 + (lane&31) (filter), k = 8*(lane>>5) + j, dword q: j=2q lo16, j=2q+1 hi16
// chunks: c<17: (ky=c, kx=k); c==17: (ky=k, kx=16); c==18: k==0 -> (ky=16,kx=16)
__global__ void k_repackB(const float* __restrict__ w, uint32_t* __restrict__ Bf) {
  int tid = blockIdx.x * 256 + threadIdx.x;
  if (tid >= 19 * 6 * 64 * 4) return;
  int q = tid & 3;
  int lane = (tid >> 2) & 63;
  int ct = tid >> 8;
  int t = ct % 6, c = ct / 6;
  int n = t * 32 + (lane & 31);
  int hf = lane >> 5;
  uint32_t hv = 0, lv = 0;
  for (int s = 0; s < 2; s++) {
    int j = 2 * q + s;
    int k = hf * 8 + j;   // 0..15
    float val = 0.f;
    if (n < NF) {
      if (c < 17)       val = w[n * 289 + c * 17 + k];
      else if (c == 17) val = w[n * 289 + k * 17 + 16];
      else if (k == 0)  val = w[n * 289 + 16 * 17 + 16];
    }
    val *= WSCALE;
    _Float16 hh = (_Float16)val;
    _Float16 ll = (_Float16)(val - (float)hh);
    hv |= (uint32_t)__builtin_bit_cast(uint16_t, hh) << (16 * s);
    lv |= (uint32_t)__builtin_bit_cast(uint16_t, ll) << (16 * s);
  }
  int base = c * 3072;
  int off = t * 256 + lane * 4 + q;
  Bf[base + off] = hv;
  Bf[base + 1536 + off] = lv;
}

// ---------------- gray ----------------
__global__ void k_gray(const float* __restrict__ x, float* __restrict__ gray) {
  int i = blockIdx.x * blockDim.x + threadIdx.x;
  if (i >= NB * NPIX) return;
  int b = i / NPIX, r = i % NPIX;
  const float* xb = x + (size_t)b * 3 * NPIX;
  gray[i] = 0.2989f * xb[r] + 0.587f * xb[NPIX + r] + 0.114f * xb[2 * NPIX + r];
}

// ---------------- vertical blur, both sigmas fused ----------------
__global__ void k_vblur2(const float* __restrict__ in, float* __restrict__ outA,
                         float* __restrict__ outB, const float* __restrict__ taps) {
  int i = blockIdx.x * blockDim.x + threadIdx.x;
  if (i >= NB * NPIX) return;
  int b = i / NPIX, r = i % NPIX;
  int y = r / W, xx = r % W;
  const float* img = in + (size_t)b * NPIX;
  float a = 0.f;
#pragma unroll
  for (int j = -2; j <= 2; j++) {
    int yy = y + j; yy = yy < 0 ? 0 : (yy > H - 1 ? H - 1 : yy);
    a = fmaf(taps[j + 2], img[yy * W + xx], a);
  }
  float c = 0.f;
  for (int j = -40; j <= 40; j++) {
    int yy = y + j; yy = yy < 0 ? 0 : (yy > H - 1 ? H - 1 : yy);
    c = fmaf(taps[8 + j + 40], img[yy * W + xx], c);
  }
  outA[i] = a;
  outB[i] = c;
}

// ---------------- horizontal blur + DoG + f16-split pack ----------------
__global__ void k_hblur_dog(const float* __restrict__ inA, const float* __restrict__ inB,
                            uint32_t* __restrict__ dogp, const float* __restrict__ taps) {
  int i = blockIdx.x * blockDim.x + threadIdx.x;
  if (i >= NB * NPIX) return;
  int b = i / NPIX, r = i % NPIX;
  int y = r / W, xx = r % W;
  const float* ra = inA + (size_t)b * NPIX + (size_t)y * W;
  const float* rb = inB + (size_t)b * NPIX + (size_t)y * W;
  float a = 0.f;
#pragma unroll
  for (int j = -2; j <= 2; j++) {
    int xc = xx + j; xc = xc < 0 ? 0 : (xc > W - 1 ? W - 1 : xc);
    a = fmaf(taps[j + 2], ra[xc], a);
  }
  float c = 0.f;
  for (int j = -40; j <= 40; j++) {
    int xc = xx + j; xc = xc < 0 ? 0 : (xc > W - 1 ? W - 1 : xc);
    c = fmaf(taps[8 + j + 40], rb[xc], c);
  }
  float d = a - c;
  _Float16 hh = (_Float16)d;
  _Float16 ll = (_Float16)(d - (float)hh);
  dogp[i] = ((uint32_t)__builtin_bit_cast(uint16_t, ll) << 16) |
            (uint32_t)__builtin_bit_cast(uint16_t, hh);
}

// ---------------- main: TRANSPOSED implicit-GEMM MFMA conv ----------------
// GEMM: A = weights (M=192 filters), B = data (N=pixels). C: col=lane&31=pixel,
// row=filter -> each lane holds 96 filters of ONE pixel in registers; the
// per-pixel argmax/sum/conf reduction is lane-local + shfl_xor(32) merges.
// W-frags read 3 tiles at a time (24 regs live, not 48) to stay under the
// 256-reg/wave cap -> no scratch spill (R13's 118 MB WRITE_SIZE).
__launch_bounds__(256, 2)
__global__ void k_conv(const uint32_t* __restrict__ dogp,
                       const uint32_t* __restrict__ Bf,
                       const float* __restrict__ bins,
                       float* __restrict__ out) {
  __shared__ uint32_t pool[POOL_U32];

  const int b  = blockIdx.z;
  const int y0 = blockIdx.y * 4;
  const int x0 = blockIdx.x * 64;
  const int tid = threadIdx.x;
  const int lane = tid & 63;
  const int w  = __builtin_amdgcn_readfirstlane(tid >> 6);  // 0..3
  const int rp2 = (w >> 1) * 2;   // 0 or 2: wave's row-pair base
  const int ch  = w & 1;          // col half (0: cols 0..31, 1: 32..63)
  const int nl = lane & 31;
  const int half = lane >> 5;

  // ---- stage raw rows y0-8 .. y0+11 (20), cols x0-8 .. x0+71 (zero-padded) ----
  const uint32_t* dgb = dogp + (size_t)b * NPIX;
  for (int i = tid; i < 20 * 80; i += 256) {
    int ry = i / 80, rx = i % 80;
    int gy = y0 + ry - 8, gx = x0 + rx - 8;
    uint32_t v = 0;
    if (gy >= 0 && gy < H && gx >= 0 && gx < W) v = dgb[gy * W + gx];
    pool[RAW_OFF + i] = v;
  }
  // ---- stage weight chunks 0,1 into phase buffer 0 ----
  {
    const uint32_t* src = Bf + (size_t)tid * 4;
    uint32_t* dst = &pool[BB_OFF + tid * 4];
#pragma unroll
    for (int i = 0; i < 6; i++) gl_lds16(src + i * 1024, dst + i * 1024);
  }
  asm volatile("s_waitcnt vmcnt(0)" ::: "memory");
  __syncthreads();

  floatx16 acc[2][6];   // [data row d][filter tile t]
#pragma unroll
  for (int d = 0; d < 2; d++)
#pragma unroll
    for (int t = 0; t < 6; t++)
#pragma unroll
      for (int q = 0; q < 16; q++) acc[d][t][q] = 0.f;

  const int abase = ch * 32 + nl + half * 8;

  // build data fragment (hi/lo) for tile row tr
  auto buildRow = [&](int tr, FragU& fh, FragU& fl) {
    const uint32_t* rp = &pool[RAW_OFF + tr * 80 + abase];
    uint32_t d[8];
#pragma unroll
    for (int j = 0; j < 8; j++) d[j] = rp[j];
#pragma unroll
    for (int q = 0; q < 4; q++) {
      fh.u[q] = __builtin_amdgcn_perm(d[2 * q + 1], d[2 * q], 0x05040100u);
      fl.u[q] = __builtin_amdgcn_perm(d[2 * q + 1], d[2 * q], 0x07060302u);
    }
  };
  // build data strip fragment for tail chunk c (17/18), data row base rb
  auto buildStrip = [&](int c, int rb, FragU& fh, FragU& fl) {
    int kyb = (c - 17) * 16 + half * 8;
    uint32_t d[8];
#pragma unroll
    for (int j = 0; j < 8; j++) {
      int ky = kyb + j; if (ky > 16) ky = 16;   // clamped reads killed by W=0
      d[j] = pool[RAW_OFF + (rb + ky) * 80 + ch * 32 + nl + 16];
    }
#pragma unroll
    for (int q = 0; q < 4; q++) {
      fh.u[q] = __builtin_amdgcn_perm(d[2 * q + 1], d[2 * q], 0x05040100u);
      fl.u[q] = __builtin_amdgcn_perm(d[2 * q + 1], d[2 * q], 0x07060302u);
    }
  };
  // half-chunk: read 3 filter tiles (hi+lo = 24 regs), 18 MFMAs; same product
  // set & order as R13 within each tile: Dh*Wh, Dl*Wh, Dh*Wl
  auto halfChunk = [&](int off, int t0, FragU& d0h, FragU& d0l, FragU& d1h, FragU& d1l) {
    FragU wh[3], wl[3];
#pragma unroll
    for (int t = 0; t < 3; t++) {
      wh[t].u = *(const u32x4*)&pool[off + (t0 + t) * 256 + lane * 4];
      wl[t].u = *(const u32x4*)&pool[off + 1536 + (t0 + t) * 256 + lane * 4];
    }
#pragma unroll
    for (int t = 0; t < 3; t++) {
      acc[0][t0 + t] = __builtin_amdgcn_mfma_f32_32x32x16_f16(wh[t].h, d0h.h, acc[0][t0 + t], 0, 0, 0);
      acc[1][t0 + t] = __builtin_amdgcn_mfma_f32_32x32x16_f16(wh[t].h, d1h.h, acc[1][t0 + t], 0, 0, 0);
    }
#pragma unroll
    for (int t = 0; t < 3; t++) {
      acc[0][t0 + t] = __builtin_amdgcn_mfma_f32_32x32x16_f16(wh[t].h, d0l.h, acc[0][t0 + t], 0, 0, 0);
      acc[1][t0 + t] = __builtin_amdgcn_mfma_f32_32x32x16_f16(wh[t].h, d1l.h, acc[1][t0 + t], 0, 0, 0);
    }
#pragma unroll
    for (int t = 0; t < 3; t++) {
      acc[0][t0 + t] = __builtin_amdgcn_mfma_f32_32x32x16_f16(wl[t].h, d0h.h, acc[0][t0 + t], 0, 0, 0);
      acc[1][t0 + t] = __builtin_amdgcn_mfma_f32_32x32x16_f16(wl[t].h, d1h.h, acc[1][t0 + t], 0, 0, 0);
    }
  };
  auto mfmaChunk = [&](int off, FragU& d0h, FragU& d0l, FragU& d1h, FragU& d1l) {
    halfChunk(off, 0, d0h, d0l, d1h, d1l);
    halfChunk(off, 3, d0h, d0l, d1h, d1l);
  };

  FragU a0h, a0l, a1h, a1l;
  buildRow(rp2, a0h, a0l);   // chunk 0, data row 0 (rolls forward)

  int buf = 0;
  for (int p = 0; p < 8; p++) {          // chunks 2p, 2p+1 (c <= 15, row-type)
    {
      const uint32_t* src = Bf + (size_t)(2 * p + 2) * BCH_U32 + (size_t)tid * 4;
      uint32_t* dst = &pool[BB_OFF + (buf ^ 1) * PH_U32 + tid * 4];
#pragma unroll
      for (int i = 0; i < 6; i++) gl_lds16(src + i * 1024, dst + i * 1024);
    }
    // chunk c0 = 2p
    buildRow(rp2 + 1 + 2 * p, a1h, a1l);
    mfmaChunk(BB_OFF + buf * PH_U32, a0h, a0l, a1h, a1l);
    a0h = a1h; a0l = a1l;
    // chunk c1 = 2p+1
    buildRow(rp2 + 2 + 2 * p, a1h, a1l);
    mfmaChunk(BB_OFF + buf * PH_U32 + BCH_U32, a0h, a0l, a1h, a1l);
    a0h = a1h; a0l = a1l;

    asm volatile("s_waitcnt vmcnt(0)" ::: "memory");
    __syncthreads();
    buf ^= 1;
  }

  // phase 8: chunks 16 (row-type, rolled) and 17 (strip); stage chunk 18
  {
    const uint32_t* src = Bf + (size_t)18 * BCH_U32 + (size_t)tid * 4;
    uint32_t* dst = &pool[BB_OFF + (buf ^ 1) * PH_U32 + tid * 4];
#pragma unroll
    for (int i = 0; i < 3; i++) gl_lds16(src + i * 1024, dst + i * 1024);

    buildRow(rp2 + 17, a1h, a1l);                   // c=16, data row 1
    mfmaChunk(BB_OFF + buf * PH_U32, a0h, a0l, a1h, a1l);

    FragU s0h, s0l, s1h, s1l;
    buildStrip(17, rp2, s0h, s0l);
    buildStrip(17, rp2 + 1, s1h, s1l);
    mfmaChunk(BB_OFF + buf * PH_U32 + BCH_U32, s0h, s0l, s1h, s1l);

    asm volatile("s_waitcnt vmcnt(0)" ::: "memory");
    __syncthreads();
    buf ^= 1;
  }
  // phase 9: chunk 18 (strip), no staging, no barrier
  {
    FragU s0h, s0l, s1h, s1l;
    buildStrip(18, rp2, s0h, s0l);
    buildStrip(18, rp2 + 1, s1h, s1l);
    mfmaChunk(BB_OFF + buf * PH_U32, s0h, s0l, s1h, s1l);
  }

  // ---- lane-local epilogue: per lane = 1 pixel x 96 filters (per d) ----
  // filter index for (t,q): n = 32t + (q&3) + 8*(q>>2) + 4*half  (increasing in t,q)
  const float PI_F = 3.14159265358979323846f;
  const float INV_PI = 0.31830988618379067154f;
  const double STEPD = 3.14159265358979323846 * 179.0 / 180.0 / 179.0;
  const float stepf = (float)STEPD;
  const float hbase = (4.0f * (float)half) * stepf;   // bin offset for this half

#pragma unroll
  for (int d = 0; d < 2; d++) {
    // exact local argmax (first-max-wins: n strictly increasing) + sum
    float m = -1.f; int n = 0; float S0 = 0.f, S1 = 0.f;
#pragma unroll
    for (int t = 0; t < 6; t++) {
#pragma unroll
      for (int q = 0; q < 16; q++) {
        float v = fabsf(acc[d][t][q]);
        if (q & 1) S1 += v; else S0 += v;
        int nf = 32 * t + (q & 3) + 8 * (q >> 2) + 4 * half;
        if (v > m) { m = v; n = nf; }
      }
    }
    float S = S0 + S1;
    // merge the two halves (lanes p <-> p+32 hold complementary filter sets)
    {
      float mo = __shfl_xor(m, 32);
      int   no = __shfl_xor(n, 32);
      float So = __shfl_xor(S, 32);
      bool take = (mo > m) || (mo == m && no < n);
      if (take) { m = mo; n = no; }
      S += So;
    }
    float om  = (float)n / 180.0f * 255.0f;
    float rad = om / 180.0f * PI_F;
    float ddc = rad - hbase;
    // confidence: dist = dd - pi*rndne(dd/pi) == min over {dd, dd-pi, dd+pi}
    float C0 = 0.f, C1 = 0.f;
#pragma unroll
    for (int t = 0; t < 6; t++) {
#pragma unroll
      for (int q = 0; q < 16; q++) {
        const float K = (float)((double)(32 * t + (q & 3) + 8 * (q >> 2)) * STEPD);
        float dd = ddc - K;
        float r = rintf(dd * INV_PI);
        float dist = fmaf(-PI_F, r, dd);
        float w2 = dist * dist;
        if (q & 1) C1 = fmaf(w2, fabsf(acc[d][t][q]), C1);
        else       C0 = fmaf(w2, fabsf(acc[d][t][q]), C0);
      }
    }
    float C = C0 + C1;
    C += __shfl_xor(C, 32);
    if (half == 0) {
      int y = y0 + rp2 + d;
      int x = x0 + ch * 32 + nl;
      out[(size_t)b * NPIX + (size_t)y * W + x] = om;
      out[(size_t)NB * NPIX + (size_t)b * NPIX + (size_t)y * W + x] = C / S;
    }
  }
}

extern "C" void kernel_launch(void* const* d_in, const int* in_sizes, int n_in,
                              void* d_out, int out_size, void* d_ws, size_t ws_size,
                              hipStream_t stream) {
  const float* x = (const float*)d_in[0];      // [2,3,512,512]
  const float* wts = (const float*)d_in[1];    // [180,1,17,17]
  const float* bins = (const float*)d_in[2];   // [180]
  float* out = (float*)d_out;

  float* ws = (float*)d_ws;
  float* gray = ws;                                 // 524288 f32
  float* tmpA = ws + (size_t)NB * NPIX;             // 524288 f32
  float* tmpB = tmpA + (size_t)NB * NPIX;           // 524288 f32
  uint32_t* dogp = (uint32_t*)(tmpB + (size_t)NB * NPIX);  // 524288 u32
  float* taps = (float*)(dogp + (size_t)NB * NPIX); // 128 f32
  uint32_t* Bf = (uint32_t*)(taps + 128);           // 19*3072 u32

  k_taps<<<1, 64, 0, stream>>>(taps);
  k_repackB<<<114, 256, 0, stream>>>(wts, Bf);

  int n = NB * NPIX;
  int blk = 256, grd = (n + blk - 1) / blk;
  k_gray<<<grd, blk, 0, stream>>>(x, gray);
  k_vblur2<<<grd, blk, 0, stream>>>(gray, tmpA, tmpB, taps);
  k_hblur_dog<<<grd, blk, 0, stream>>>(tmpA, tmpB, dogp, taps);

  dim3 g(W / 64, H / 4, NB);
  k_conv<<<g, 256, 0, stream>>>(dogp, Bf, bins, out);
}

// Round 15
// 200.391 us; speedup vs baseline: 1.4285x; 1.0324x over previous
//
#include <hip/hip_runtime.h>
#include <math.h>
#include <stdint.h>

#define H 512
#define W 512
#define NPIX (H * W)          // 262144
#define NB 2
#define NF 180
#define KS 17
#define WSCALE 1024.0f        // exact power of two; cancels in both outputs

// LDS pool (u32): raw rows 20*80=1600; B double buffer 2 phases * 2 chunks * 3072
#define RAW_OFF 0
#define BB_OFF  1600
#define BCH_U32 3072          // one K-chunk of weights (hi+lo, 192 filters), 12 KB
#define PH_U32  (2 * BCH_U32) // 2-chunk phase buffer, 24 KB
#define POOL_U32 (1600 + 2 * PH_U32)   // 13888 u32 = 55.5 KB

typedef _Float16 half8 __attribute__((ext_vector_type(8)));
typedef float floatx16 __attribute__((ext_vector_type(16)));
typedef uint32_t u32x4 __attribute__((ext_vector_type(4)));

union FragU { u32x4 u; half8 h; };

__device__ inline void gl_lds16(const uint32_t* g, uint32_t* l) {
  __builtin_amdgcn_global_load_lds((const __attribute__((address_space(1))) void*)g,
                                   (__attribute__((address_space(3))) void*)l, 16, 0, 0);
}

// ---------------- taps (match numpy float64 _gauss1d) ----------------
__global__ void k_taps(float* __restrict__ taps) {
  if (threadIdx.x == 0 && blockIdx.x == 0) {
    {
      double k[5], s = 0.0;
      for (int i = 0; i < 5; i++) { double xv = (double)(i - 2) / 0.4; k[i] = exp(-0.5 * xv * xv); s += k[i]; }
      for (int i = 0; i < 5; i++) taps[i] = (float)(k[i] / s);
    }
    {
      double k[81], s = 0.0;
      for (int i = 0; i < 81; i++) { double xv = (double)(i - 40) / 10.0; k[i] = exp(-0.5 * xv * xv); s += k[i]; }
      for (int i = 0; i < 81; i++) taps[8 + i] = (float)(k[i] / s);
    }
  }
}

// ---------------- weight repack into MFMA fragment order, f16 split ----------------
// Bf (u32): chunk c (19): [c*3072 ..]: hi frags: t*256 + lane*4 + q ; lo at +1536
// W[m][k]: m = t*32 + (lane&31) (filter), k = 8*(lane>>5) + j, dword q: j=2q lo16, j=2q+1 hi16
// chunks: c<17: (ky=c, kx=k); c==17: (ky=k, kx=16); c==18: k==0 -> (ky=16,kx=16)
__global__ void k_repackB(const float* __restrict__ w, uint32_t* __restrict__ Bf) {
  int tid = blockIdx.x * 256 + threadIdx.x;
  if (tid >= 19 * 6 * 64 * 4) return;
  int q = tid & 3;
  int lane = (tid >> 2) & 63;
  int ct = tid >> 8;
  int t = ct % 6, c = ct / 6;
  int n = t * 32 + (lane & 31);
  int hf = lane >> 5;
  uint32_t hv = 0, lv = 0;
  for (int s = 0; s < 2; s++) {
    int j = 2 * q + s;
    int k = hf * 8 + j;   // 0..15
    float val = 0.f;
    if (n < NF) {
      if (c < 17)       val = w[n * 289 + c * 17 + k];
      else if (c == 17) val = w[n * 289 + k * 17 + 16];
      else if (k == 0)  val = w[n * 289 + 16 * 17 + 16];
    }
    val *= WSCALE;
    _Float16 hh = (_Float16)val;
    _Float16 ll = (_Float16)(val - (float)hh);
    hv |= (uint32_t)__builtin_bit_cast(uint16_t, hh) << (16 * s);
    lv |= (uint32_t)__builtin_bit_cast(uint16_t, ll) << (16 * s);
  }
  int base = c * 3072;
  int off = t * 256 + lane * 4 + q;
  Bf[base + off] = hv;
  Bf[base + 1536 + off] = lv;
}

// ---------------- gray ----------------
__global__ void k_gray(const float* __restrict__ x, float* __restrict__ gray) {
  int i = blockIdx.x * blockDim.x + threadIdx.x;
  if (i >= NB * NPIX) return;
  int b = i / NPIX, r = i % NPIX;
  const float* xb = x + (size_t)b * 3 * NPIX;
  gray[i] = 0.2989f * xb[r] + 0.587f * xb[NPIX + r] + 0.114f * xb[2 * NPIX + r];
}

// ---------------- vertical blur, both sigmas fused ----------------
__global__ void k_vblur2(const float* __restrict__ in, float* __restrict__ outA,
                         float* __restrict__ outB, const float* __restrict__ taps) {
  int i = blockIdx.x * blockDim.x + threadIdx.x;
  if (i >= NB * NPIX) return;
  int b = i / NPIX, r = i % NPIX;
  int y = r / W, xx = r % W;
  const float* img = in + (size_t)b * NPIX;
  float a = 0.f;
#pragma unroll
  for (int j = -2; j <= 2; j++) {
    int yy = y + j; yy = yy < 0 ? 0 : (yy > H - 1 ? H - 1 : yy);
    a = fmaf(taps[j + 2], img[yy * W + xx], a);
  }
  float c = 0.f;
  for (int j = -40; j <= 40; j++) {
    int yy = y + j; yy = yy < 0 ? 0 : (yy > H - 1 ? H - 1 : yy);
    c = fmaf(taps[8 + j + 40], img[yy * W + xx], c);
  }
  outA[i] = a;
  outB[i] = c;
}

// ---------------- horizontal blur + DoG + f16-split pack ----------------
__global__ void k_hblur_dog(const float* __restrict__ inA, const float* __restrict__ inB,
                            uint32_t* __restrict__ dogp, const float* __restrict__ taps) {
  int i = blockIdx.x * blockDim.x + threadIdx.x;
  if (i >= NB * NPIX) return;
  int b = i / NPIX, r = i % NPIX;
  int y = r / W, xx = r % W;
  const float* ra = inA + (size_t)b * NPIX + (size_t)y * W;
  const float* rb = inB + (size_t)b * NPIX + (size_t)y * W;
  float a = 0.f;
#pragma unroll
  for (int j = -2; j <= 2; j++) {
    int xc = xx + j; xc = xc < 0 ? 0 : (xc > W - 1 ? W - 1 : xc);
    a = fmaf(taps[j + 2], ra[xc], a);
  }
  float c = 0.f;
  for (int j = -40; j <= 40; j++) {
    int xc = xx + j; xc = xc < 0 ? 0 : (xc > W - 1 ? W - 1 : xc);
    c = fmaf(taps[8 + j + 40], rb[xc], c);
  }
  float d = a - c;
  _Float16 hh = (_Float16)d;
  _Float16 ll = (_Float16)(d - (float)hh);
  dogp[i] = ((uint32_t)__builtin_bit_cast(uint16_t, ll) << 16) |
            (uint32_t)__builtin_bit_cast(uint16_t, hh);
}

// ---------------- main: TRANSPOSED implicit-GEMM MFMA conv ----------------
// GEMM: A = weights (M=192 filters), B = data (N=pixels). C: col=lane&31=pixel,
// row=filter -> each lane holds 96 filters of ONE pixel in registers; the
// per-pixel argmax/sum/conf reduction is lane-local + shfl_xor(32) merges.
// launch_bounds(256,1): 512 unified regs/wave -> NO scratch spill (R14's 94 MB).
// 1 wave/SIMD; the block's 4 waves overlap MFMA (own SIMD) with LDS pipe.
__launch_bounds__(256, 1)
__global__ void k_conv(const uint32_t* __restrict__ dogp,
                       const uint32_t* __restrict__ Bf,
                       const float* __restrict__ bins,
                       float* __restrict__ out) {
  __shared__ uint32_t pool[POOL_U32];

  const int b  = blockIdx.z;
  const int y0 = blockIdx.y * 4;
  const int x0 = blockIdx.x * 64;
  const int tid = threadIdx.x;
  const int lane = tid & 63;
  const int w  = __builtin_amdgcn_readfirstlane(tid >> 6);  // 0..3
  const int rp2 = (w >> 1) * 2;   // 0 or 2: wave's row-pair base
  const int ch  = w & 1;          // col half (0: cols 0..31, 1: 32..63)
  const int nl = lane & 31;
  const int half = lane >> 5;

  // ---- stage raw rows y0-8 .. y0+11 (20), cols x0-8 .. x0+71 (zero-padded) ----
  const uint32_t* dgb = dogp + (size_t)b * NPIX;
  for (int i = tid; i < 20 * 80; i += 256) {
    int ry = i / 80, rx = i % 80;
    int gy = y0 + ry - 8, gx = x0 + rx - 8;
    uint32_t v = 0;
    if (gy >= 0 && gy < H && gx >= 0 && gx < W) v = dgb[gy * W + gx];
    pool[RAW_OFF + i] = v;
  }
  // ---- stage weight chunks 0,1 into phase buffer 0 ----
  {
    const uint32_t* src = Bf + (size_t)tid * 4;
    uint32_t* dst = &pool[BB_OFF + tid * 4];
#pragma unroll
    for (int i = 0; i < 6; i++) gl_lds16(src + i * 1024, dst + i * 1024);
  }
  asm volatile("s_waitcnt vmcnt(0)" ::: "memory");
  __syncthreads();

  floatx16 acc[2][6];   // [data row d][filter tile t]
#pragma unroll
  for (int d = 0; d < 2; d++)
#pragma unroll
    for (int t = 0; t < 6; t++)
#pragma unroll
      for (int q = 0; q < 16; q++) acc[d][t][q] = 0.f;

  const int abase = ch * 32 + nl + half * 8;

  // build data fragment (hi/lo) for tile row tr
  auto buildRow = [&](int tr, FragU& fh, FragU& fl) {
    const uint32_t* rp = &pool[RAW_OFF + tr * 80 + abase];
    uint32_t d[8];
#pragma unroll
    for (int j = 0; j < 8; j++) d[j] = rp[j];
#pragma unroll
    for (int q = 0; q < 4; q++) {
      fh.u[q] = __builtin_amdgcn_perm(d[2 * q + 1], d[2 * q], 0x05040100u);
      fl.u[q] = __builtin_amdgcn_perm(d[2 * q + 1], d[2 * q], 0x07060302u);
    }
  };
  // build data strip fragment for tail chunk c (17/18), data row base rb
  auto buildStrip = [&](int c, int rb, FragU& fh, FragU& fl) {
    int kyb = (c - 17) * 16 + half * 8;
    uint32_t d[8];
#pragma unroll
    for (int j = 0; j < 8; j++) {
      int ky = kyb + j; if (ky > 16) ky = 16;   // clamped reads killed by W=0
      d[j] = pool[RAW_OFF + (rb + ky) * 80 + ch * 32 + nl + 16];
    }
#pragma unroll
    for (int q = 0; q < 4; q++) {
      fh.u[q] = __builtin_amdgcn_perm(d[2 * q + 1], d[2 * q], 0x05040100u);
      fl.u[q] = __builtin_amdgcn_perm(d[2 * q + 1], d[2 * q], 0x07060302u);
    }
  };
  // half-chunk: read 3 filter tiles (hi+lo = 24 regs), 18 MFMAs; same product
  // set & order: Dh*Wh, Dl*Wh, Dh*Wl
  auto halfChunk = [&](int off, int t0, FragU& d0h, FragU& d0l, FragU& d1h, FragU& d1l) {
    FragU wh[3], wl[3];
#pragma unroll
    for (int t = 0; t < 3; t++) {
      wh[t].u = *(const u32x4*)&pool[off + (t0 + t) * 256 + lane * 4];
      wl[t].u = *(const u32x4*)&pool[off + 1536 + (t0 + t) * 256 + lane * 4];
    }
#pragma unroll
    for (int t = 0; t < 3; t++) {
      acc[0][t0 + t] = __builtin_amdgcn_mfma_f32_32x32x16_f16(wh[t].h, d0h.h, acc[0][t0 + t], 0, 0, 0);
      acc[1][t0 + t] = __builtin_amdgcn_mfma_f32_32x32x16_f16(wh[t].h, d1h.h, acc[1][t0 + t], 0, 0, 0);
    }
#pragma unroll
    for (int t = 0; t < 3; t++) {
      acc[0][t0 + t] = __builtin_amdgcn_mfma_f32_32x32x16_f16(wh[t].h, d0l.h, acc[0][t0 + t], 0, 0, 0);
      acc[1][t0 + t] = __builtin_amdgcn_mfma_f32_32x32x16_f16(wh[t].h, d1l.h, acc[1][t0 + t], 0, 0, 0);
    }
#pragma unroll
    for (int t = 0; t < 3; t++) {
      acc[0][t0 + t] = __builtin_amdgcn_mfma_f32_32x32x16_f16(wl[t].h, d0h.h, acc[0][t0 + t], 0, 0, 0);
      acc[1][t0 + t] = __builtin_amdgcn_mfma_f32_32x32x16_f16(wl[t].h, d1h.h, acc[1][t0 + t], 0, 0, 0);
    }
  };
  auto mfmaChunk = [&](int off, FragU& d0h, FragU& d0l, FragU& d1h, FragU& d1l) {
    halfChunk(off, 0, d0h, d0l, d1h, d1l);
    halfChunk(off, 3, d0h, d0l, d1h, d1l);
  };

  FragU a0h, a0l, a1h, a1l;
  buildRow(rp2, a0h, a0l);   // chunk 0, data row 0 (rolls forward)

  int buf = 0;
  for (int p = 0; p < 8; p++) {          // chunks 2p, 2p+1 (c <= 15, row-type)
    {
      const uint32_t* src = Bf + (size_t)(2 * p + 2) * BCH_U32 + (size_t)tid * 4;
      uint32_t* dst = &pool[BB_OFF + (buf ^ 1) * PH_U32 + tid * 4];
#pragma unroll
      for (int i = 0; i < 6; i++) gl_lds16(src + i * 1024, dst + i * 1024);
    }
    // chunk c0 = 2p
    buildRow(rp2 + 1 + 2 * p, a1h, a1l);
    mfmaChunk(BB_OFF + buf * PH_U32, a0h, a0l, a1h, a1l);
    a0h = a1h; a0l = a1l;
    // chunk c1 = 2p+1
    buildRow(rp2 + 2 + 2 * p, a1h, a1l);
    mfmaChunk(BB_OFF + buf * PH_U32 + BCH_U32, a0h, a0l, a1h, a1l);
    a0h = a1h; a0l = a1l;

    asm volatile("s_waitcnt vmcnt(0)" ::: "memory");
    __syncthreads();
    buf ^= 1;
  }

  // phase 8: chunks 16 (row-type, rolled) and 17 (strip); stage chunk 18
  {
    const uint32_t* src = Bf + (size_t)18 * BCH_U32 + (size_t)tid * 4;
    uint32_t* dst = &pool[BB_OFF + (buf ^ 1) * PH_U32 + tid * 4];
#pragma unroll
    for (int i = 0; i < 3; i++) gl_lds16(src + i * 1024, dst + i * 1024);

    buildRow(rp2 + 17, a1h, a1l);                   // c=16, data row 1
    mfmaChunk(BB_OFF + buf * PH_U32, a0h, a0l, a1h, a1l);

    FragU s0h, s0l, s1h, s1l;
    buildStrip(17, rp2, s0h, s0l);
    buildStrip(17, rp2 + 1, s1h, s1l);
    mfmaChunk(BB_OFF + buf * PH_U32 + BCH_U32, s0h, s0l, s1h, s1l);

    asm volatile("s_waitcnt vmcnt(0)" ::: "memory");
    __syncthreads();
    buf ^= 1;
  }
  // phase 9: chunk 18 (strip), no staging, no barrier
  {
    FragU s0h, s0l, s1h, s1l;
    buildStrip(18, rp2, s0h, s0l);
    buildStrip(18, rp2 + 1, s1h, s1l);
    mfmaChunk(BB_OFF + buf * PH_U32, s0h, s0l, s1h, s1l);
  }

  // ---- lane-local epilogue: per lane = 1 pixel x 96 filters (per d) ----
  // filter index for (t,q): n = 32t + (q&3) + 8*(q>>2) + 4*half  (increasing in t,q)
  const float PI_F = 3.14159265358979323846f;
  const float INV_PI = 0.31830988618379067154f;
  const double STEPD = 3.14159265358979323846 * 179.0 / 180.0 / 179.0;
  const float stepf = (float)STEPD;
  const float hbase = (4.0f * (float)half) * stepf;   // bin offset for this half

#pragma unroll
  for (int d = 0; d < 2; d++) {
    // exact local argmax (first-max-wins: n strictly increasing) + sum
    float m = -1.f; int n = 0; float S0 = 0.f, S1 = 0.f;
#pragma unroll
    for (int t = 0; t < 6; t++) {
#pragma unroll
      for (int q = 0; q < 16; q++) {
        float v = fabsf(acc[d][t][q]);
        if (q & 1) S1 += v; else S0 += v;
        int nf = 32 * t + (q & 3) + 8 * (q >> 2) + 4 * half;
        if (v > m) { m = v; n = nf; }
      }
    }
    float S = S0 + S1;
    // merge the two halves (lanes p <-> p+32 hold complementary filter sets)
    {
      float mo = __shfl_xor(m, 32);
      int   no = __shfl_xor(n, 32);
      float So = __shfl_xor(S, 32);
      bool take = (mo > m) || (mo == m && no < n);
      if (take) { m = mo; n = no; }
      S += So;
    }
    float om  = (float)n / 180.0f * 255.0f;
    float rad = om / 180.0f * PI_F;
    float ddc = rad - hbase;
    // confidence: dist = dd - pi*rndne(dd/pi) == min over {dd, dd-pi, dd+pi}
    float C0 = 0.f, C1 = 0.f;
#pragma unroll
    for (int t = 0; t < 6; t++) {
#pragma unroll
      for (int q = 0; q < 16; q++) {
        const float K = (float)((double)(32 * t + (q & 3) + 8 * (q >> 2)) * STEPD);
        float dd = ddc - K;
        float r = rintf(dd * INV_PI);
        float dist = fmaf(-PI_F, r, dd);
        float w2 = dist * dist;
        if (q & 1) C1 = fmaf(w2, fabsf(acc[d][t][q]), C1);
        else       C0 = fmaf(w2, fabsf(acc[d][t][q]), C0);
      }
    }
    float C = C0 + C1;
    C += __shfl_xor(C, 32);
    if (half == 0) {
      int y = y0 + rp2 + d;
      int x = x0 + ch * 32 + nl;
      out[(size_t)b * NPIX + (size_t)y * W + x] = om;
      out[(size_t)NB * NPIX + (size_t)b * NPIX + (size_t)y * W + x] = C / S;
    }
  }
}

extern "C" void kernel_launch(void* const* d_in, const int* in_sizes, int n_in,
                              void* d_out, int out_size, void* d_ws, size_t ws_size,
                              hipStream_t stream) {
  const float* x = (const float*)d_in[0];      // [2,3,512,512]
  const float* wts = (const float*)d_in[1];    // [180,1,17,17]
  const float* bins = (const float*)d_in[2];   // [180]
  float* out = (float*)d_out;

  float* ws = (float*)d_ws;
  float* gray = ws;                                 // 524288 f32
  float* tmpA = ws + (size_t)NB * NPIX;             // 524288 f32
  float* tmpB = tmpA + (size_t)NB * NPIX;           // 524288 f32
  uint32_t* dogp = (uint32_t*)(tmpB + (size_t)NB * NPIX);  // 524288 u32
  float* taps = (float*)(dogp + (size_t)NB * NPIX); // 128 f32
  uint32_t* Bf = (uint32_t*)(taps + 128);           // 19*3072 u32

  k_taps<<<1, 64, 0, stream>>>(taps);
  k_repackB<<<114, 256, 0, stream>>>(wts, Bf);

  int n = NB * NPIX;
  int blk = 256, grd = (n + blk - 1) / blk;
  k_gray<<<grd, blk, 0, stream>>>(x, gray);
  k_vblur2<<<grd, blk, 0, stream>>>(gray, tmpA, tmpB, taps);
  k_hblur_dog<<<grd, blk, 0, stream>>>(tmpA, tmpB, dogp, taps);

  dim3 g(W / 64, H / 4, NB);
  k_conv<<<g, 256, 0, stream>>>(dogp, Bf, bins, out);
}

// Round 16
// 193.813 us; speedup vs baseline: 1.4770x; 1.0339x over previous
//
#include <hip/hip_runtime.h>
#include <math.h>
#include <stdint.h>

#define H 512
#define W 512
#define NPIX (H * W)          // 262144
#define NB 2
#define NF 180
#define KS 17
#define WSCALE 1024.0f        // exact power of two; cancels in both outputs

// LDS pool (u32): raw rows 20*80=1600; W double buffer 2 phases * 2 chunks * 3072
#define RAW_OFF 0
#define BB_OFF  1600
#define BCH_U32 3072          // one K-chunk of weights (hi+lo, 192 filters), 12 KB
#define PH_U32  (2 * BCH_U32) // 2-chunk phase buffer, 24 KB
#define POOL_U32 (1600 + 2 * PH_U32)   // 13888 u32 = 55.5 KB

typedef _Float16 half8 __attribute__((ext_vector_type(8)));
typedef float floatx16 __attribute__((ext_vector_type(16)));
typedef uint32_t u32x4 __attribute__((ext_vector_type(4)));

union FragU { u32x4 u; half8 h; };

__device__ inline void gl_lds16(const uint32_t* g, uint32_t* l) {
  __builtin_amdgcn_global_load_lds((const __attribute__((address_space(1))) void*)g,
                                   (__attribute__((address_space(3))) void*)l, 16, 0, 0);
}

// ---------------- taps (match numpy float64 _gauss1d) ----------------
__global__ void k_taps(float* __restrict__ taps) {
  if (threadIdx.x == 0 && blockIdx.x == 0) {
    {
      double k[5], s = 0.0;
      for (int i = 0; i < 5; i++) { double xv = (double)(i - 2) / 0.4; k[i] = exp(-0.5 * xv * xv); s += k[i]; }
      for (int i = 0; i < 5; i++) taps[i] = (float)(k[i] / s);
    }
    {
      double k[81], s = 0.0;
      for (int i = 0; i < 81; i++) { double xv = (double)(i - 40) / 10.0; k[i] = exp(-0.5 * xv * xv); s += k[i]; }
      for (int i = 0; i < 81; i++) taps[8 + i] = (float)(k[i] / s);
    }
  }
}

// ---------------- weight repack into MFMA fragment order, f16 split ----------------
// Bf (u32): chunk c (19): [c*3072 ..]: hi frags: t*256 + lane*4 + q ; lo at +1536
// W[m][k]: m = t*32 + (lane&31) (filter), k = 8*(lane>>5) + j, dword q: j=2q lo16, j=2q+1 hi16
// chunks: c<17: (ky=c, kx=k); c==17: (ky=k, kx=16); c==18: k==0 -> (ky=16,kx=16)
__global__ void k_repackB(const float* __restrict__ w, uint32_t* __restrict__ Bf) {
  int tid = blockIdx.x * 256 + threadIdx.x;
  if (tid >= 19 * 6 * 64 * 4) return;
  int q = tid & 3;
  int lane = (tid >> 2) & 63;
  int ct = tid >> 8;
  int t = ct % 6, c = ct / 6;
  int n = t * 32 + (lane & 31);
  int hf = lane >> 5;
  uint32_t hv = 0, lv = 0;
  for (int s = 0; s < 2; s++) {
    int j = 2 * q + s;
    int k = hf * 8 + j;   // 0..15
    float val = 0.f;
    if (n < NF) {
      if (c < 17)       val = w[n * 289 + c * 17 + k];
      else if (c == 17) val = w[n * 289 + k * 17 + 16];
      else if (k == 0)  val = w[n * 289 + 16 * 17 + 16];
    }
    val *= WSCALE;
    _Float16 hh = (_Float16)val;
    _Float16 ll = (_Float16)(val - (float)hh);
    hv |= (uint32_t)__builtin_bit_cast(uint16_t, hh) << (16 * s);
    lv |= (uint32_t)__builtin_bit_cast(uint16_t, ll) << (16 * s);
  }
  int base = c * 3072;
  int off = t * 256 + lane * 4 + q;
  Bf[base + off] = hv;
  Bf[base + 1536 + off] = lv;
}

// ---------------- gray ----------------
__global__ void k_gray(const float* __restrict__ x, float* __restrict__ gray) {
  int i = blockIdx.x * blockDim.x + threadIdx.x;
  if (i >= NB * NPIX) return;
  int b = i / NPIX, r = i % NPIX;
  const float* xb = x + (size_t)b * 3 * NPIX;
  gray[i] = 0.2989f * xb[r] + 0.587f * xb[NPIX + r] + 0.114f * xb[2 * NPIX + r];
}

// ---------------- vertical blur, both sigmas fused ----------------
__global__ void k_vblur2(const float* __restrict__ in, float* __restrict__ outA,
                         float* __restrict__ outB, const float* __restrict__ taps) {
  int i = blockIdx.x * blockDim.x + threadIdx.x;
  if (i >= NB * NPIX) return;
  int b = i / NPIX, r = i % NPIX;
  int y = r / W, xx = r % W;
  const float* img = in + (size_t)b * NPIX;
  float a = 0.f;
#pragma unroll
  for (int j = -2; j <= 2; j++) {
    int yy = y + j; yy = yy < 0 ? 0 : (yy > H - 1 ? H - 1 : yy);
    a = fmaf(taps[j + 2], img[yy * W + xx], a);
  }
  float c = 0.f;
  for (int j = -40; j <= 40; j++) {
    int yy = y + j; yy = yy < 0 ? 0 : (yy > H - 1 ? H - 1 : yy);
    c = fmaf(taps[8 + j + 40], img[yy * W + xx], c);
  }
  outA[i] = a;
  outB[i] = c;
}

// ---------------- horizontal blur + DoG + f16-split pack ----------------
__global__ void k_hblur_dog(const float* __restrict__ inA, const float* __restrict__ inB,
                            uint32_t* __restrict__ dogp, const float* __restrict__ taps) {
  int i = blockIdx.x * blockDim.x + threadIdx.x;
  if (i >= NB * NPIX) return;
  int b = i / NPIX, r = i % NPIX;
  int y = r / W, xx = r % W;
  const float* ra = inA + (size_t)b * NPIX + (size_t)y * W;
  const float* rb = inB + (size_t)b * NPIX + (size_t)y * W;
  float a = 0.f;
#pragma unroll
  for (int j = -2; j <= 2; j++) {
    int xc = xx + j; xc = xc < 0 ? 0 : (xc > W - 1 ? W - 1 : xc);
    a = fmaf(taps[j + 2], ra[xc], a);
  }
  float c = 0.f;
  for (int j = -40; j <= 40; j++) {
    int xc = xx + j; xc = xc < 0 ? 0 : (xc > W - 1 ? W - 1 : xc);
    c = fmaf(taps[8 + j + 40], rb[xc], c);
  }
  float d = a - c;
  _Float16 hh = (_Float16)d;
  _Float16 ll = (_Float16)(d - (float)hh);
  dogp[i] = ((uint32_t)__builtin_bit_cast(uint16_t, ll) << 16) |
            (uint32_t)__builtin_bit_cast(uint16_t, hh);
}

// ---------------- main: TRANSPOSED implicit-GEMM, filter-split waves ----------------
// block: 512 thr = 8 waves; w: fg=w&1 (filter group: tiles 3fg..3fg+2),
// ch=(w>>1)&1 (col half), rp2=(w>>2)*2 (row pair).
// wave: 2 data rows x 32 cols x 96 filters -> acc = 96 regs -> 2 waves/SIMD, no spill.
// Per-pixel reduction: lane-local + shfl_xor(32) + 4-stage LDS merge across fg.
__launch_bounds__(512, 2)
__global__ void k_conv(const uint32_t* __restrict__ dogp,
                       const uint32_t* __restrict__ Bf,
                       const float* __restrict__ bins,
                       float* __restrict__ out) {
  __shared__ uint32_t pool[POOL_U32];

  const int b  = blockIdx.z;
  const int y0 = blockIdx.y * 4;
  const int x0 = blockIdx.x * 64;
  const int tid = threadIdx.x;
  const int lane = tid & 63;
  const int w  = __builtin_amdgcn_readfirstlane(tid >> 6);  // 0..7
  const int fg  = w & 1;          // filter group (tiles 3fg .. 3fg+2)
  const int ch  = (w >> 1) & 1;   // col half
  const int rp2 = (w >> 2) * 2;   // row-pair base (0 or 2)
  const int nl = lane & 31;
  const int half = lane >> 5;

  // ---- stage raw rows y0-8 .. y0+11 (20), cols x0-8 .. x0+71 (zero-padded) ----
  const uint32_t* dgb = dogp + (size_t)b * NPIX;
  for (int i = tid; i < 20 * 80; i += 512) {
    int ry = i / 80, rx = i % 80;
    int gy = y0 + ry - 8, gx = x0 + rx - 8;
    uint32_t v = 0;
    if (gy >= 0 && gy < H && gx >= 0 && gx < W) v = dgb[gy * W + gx];
    pool[RAW_OFF + i] = v;
  }
  // ---- stage weight chunks 0,1 into phase buffer 0 (6144 u32, 3 rounds) ----
  {
    const uint32_t* src = Bf + (size_t)tid * 4;
    uint32_t* dst = &pool[BB_OFF + tid * 4];
#pragma unroll
    for (int i = 0; i < 3; i++) gl_lds16(src + i * 2048, dst + i * 2048);
  }
  asm volatile("s_waitcnt vmcnt(0)" ::: "memory");
  __syncthreads();

  floatx16 acc[2][3];   // [data row d][filter tile t within group]
#pragma unroll
  for (int d = 0; d < 2; d++)
#pragma unroll
    for (int t = 0; t < 3; t++)
#pragma unroll
      for (int q = 0; q < 16; q++) acc[d][t][q] = 0.f;

  const int abase = ch * 32 + nl + half * 8;

  // build data fragment (hi/lo) for tile row tr
  auto buildRow = [&](int tr, FragU& fh, FragU& fl) {
    const uint32_t* rp = &pool[RAW_OFF + tr * 80 + abase];
    uint32_t d[8];
#pragma unroll
    for (int j = 0; j < 8; j++) d[j] = rp[j];
#pragma unroll
    for (int q = 0; q < 4; q++) {
      fh.u[q] = __builtin_amdgcn_perm(d[2 * q + 1], d[2 * q], 0x05040100u);
      fl.u[q] = __builtin_amdgcn_perm(d[2 * q + 1], d[2 * q], 0x07060302u);
    }
  };
  // build data strip fragment for tail chunk c (17/18), data row base rb
  auto buildStrip = [&](int c, int rb, FragU& fh, FragU& fl) {
    int kyb = (c - 17) * 16 + half * 8;
    uint32_t d[8];
#pragma unroll
    for (int j = 0; j < 8; j++) {
      int ky = kyb + j; if (ky > 16) ky = 16;   // clamped reads killed by W=0
      d[j] = pool[RAW_OFF + (rb + ky) * 80 + ch * 32 + nl + 16];
    }
#pragma unroll
    for (int q = 0; q < 4; q++) {
      fh.u[q] = __builtin_amdgcn_perm(d[2 * q + 1], d[2 * q], 0x05040100u);
      fl.u[q] = __builtin_amdgcn_perm(d[2 * q + 1], d[2 * q], 0x07060302u);
    }
  };
  // one K-chunk: 6 W-frag b128 reads (this group's 3 tiles, hi+lo), 18 MFMAs;
  // product order per acc: Wh*Dh, Wh*Dl, Wl*Dh (same as R15)
  auto mfmaChunk = [&](int off, FragU& d0h, FragU& d0l, FragU& d1h, FragU& d1l) {
    FragU wh[3], wl[3];
#pragma unroll
    for (int t = 0; t < 3; t++) {
      wh[t].u = *(const u32x4*)&pool[off + (3 * fg + t) * 256 + lane * 4];
      wl[t].u = *(const u32x4*)&pool[off + 1536 + (3 * fg + t) * 256 + lane * 4];
    }
#pragma unroll
    for (int t = 0; t < 3; t++) {
      acc[0][t] = __builtin_amdgcn_mfma_f32_32x32x16_f16(wh[t].h, d0h.h, acc[0][t], 0, 0, 0);
      acc[1][t] = __builtin_amdgcn_mfma_f32_32x32x16_f16(wh[t].h, d1h.h, acc[1][t], 0, 0, 0);
    }
#pragma unroll
    for (int t = 0; t < 3; t++) {
      acc[0][t] = __builtin_amdgcn_mfma_f32_32x32x16_f16(wh[t].h, d0l.h, acc[0][t], 0, 0, 0);
      acc[1][t] = __builtin_amdgcn_mfma_f32_32x32x16_f16(wh[t].h, d1l.h, acc[1][t], 0, 0, 0);
    }
#pragma unroll
    for (int t = 0; t < 3; t++) {
      acc[0][t] = __builtin_amdgcn_mfma_f32_32x32x16_f16(wl[t].h, d0h.h, acc[0][t], 0, 0, 0);
      acc[1][t] = __builtin_amdgcn_mfma_f32_32x32x16_f16(wl[t].h, d1h.h, acc[1][t], 0, 0, 0);
    }
  };

  FragU a0h, a0l, a1h, a1l;
  buildRow(rp2, a0h, a0l);   // chunk 0, data row 0 (rolls forward)

  int buf = 0;
  for (int p = 0; p < 8; p++) {          // chunks 2p, 2p+1 (c <= 15, row-type)
    {
      const uint32_t* src = Bf + (size_t)(2 * p + 2) * BCH_U32 + (size_t)tid * 4;
      uint32_t* dst = &pool[BB_OFF + (buf ^ 1) * PH_U32 + tid * 4];
#pragma unroll
      for (int i = 0; i < 3; i++) gl_lds16(src + i * 2048, dst + i * 2048);
    }
    // chunk c0 = 2p
    buildRow(rp2 + 1 + 2 * p, a1h, a1l);
    mfmaChunk(BB_OFF + buf * PH_U32, a0h, a0l, a1h, a1l);
    a0h = a1h; a0l = a1l;
    // chunk c1 = 2p+1
    buildRow(rp2 + 2 + 2 * p, a1h, a1l);
    mfmaChunk(BB_OFF + buf * PH_U32 + BCH_U32, a0h, a0l, a1h, a1l);
    a0h = a1h; a0l = a1l;

    asm volatile("s_waitcnt vmcnt(0)" ::: "memory");
    __syncthreads();
    buf ^= 1;
  }

  // phase 8: chunks 16 (row-type, rolled) and 17 (strip); stage chunk 18
  {
    const uint32_t* src = Bf + (size_t)18 * BCH_U32 + (size_t)tid * 4;
    uint32_t* dst = &pool[BB_OFF + (buf ^ 1) * PH_U32 + tid * 4];
    gl_lds16(src, dst);
    if (tid < 256) gl_lds16(src + 2048, dst + 2048);

    buildRow(rp2 + 17, a1h, a1l);                   // c=16, data row 1
    mfmaChunk(BB_OFF + buf * PH_U32, a0h, a0l, a1h, a1l);

    FragU s0h, s0l, s1h, s1l;
    buildStrip(17, rp2, s0h, s0l);
    buildStrip(17, rp2 + 1, s1h, s1l);
    mfmaChunk(BB_OFF + buf * PH_U32 + BCH_U32, s0h, s0l, s1h, s1l);

    asm volatile("s_waitcnt vmcnt(0)" ::: "memory");
    __syncthreads();
    buf ^= 1;
  }
  // phase 9: chunk 18 (strip), no staging
  {
    FragU s0h, s0l, s1h, s1l;
    buildStrip(18, rp2, s0h, s0l);
    buildStrip(18, rp2 + 1, s1h, s1l);
    mfmaChunk(BB_OFF + buf * PH_U32, s0h, s0l, s1h, s1l);
  }
  __syncthreads();   // all LDS regions dead; safe to alias for epilogue

  // ---- epilogue: lane-local per group, 4-stage LDS merge across fg ----
  float* pm = (float*)&pool[0];      // [rd(4)][fg(2)][64]
  int*   pn = (int*)&pool[512];
  float* pS = (float*)&pool[1024];
  float* pc = (float*)&pool[1536];
  int*   fn = (int*)&pool[2048];     // [rd(4)][64]
  float* fS = (float*)&pool[2304];

  const float PI_F = 3.14159265358979323846f;
  const float INV_PI = 0.31830988618379067154f;
  const double STEPD = 3.14159265358979323846 * 179.0 / 180.0 / 179.0;
  const float stepf = (float)STEPD;
  const float hbase = (4.0f * (float)half) * stepf;
  const int colp = ch * 32 + nl;

  // stage 1: per-wave lane-local argmax/sum over its 48 filters, half-merged
#pragma unroll
  for (int d = 0; d < 2; d++) {
    float m = -1.f; int n = 0; float S0 = 0.f, S1 = 0.f;
#pragma unroll
    for (int t = 0; t < 3; t++) {
#pragma unroll
      for (int q = 0; q < 16; q++) {
        float v = fabsf(acc[d][t][q]);
        if (q & 1) S1 += v; else S0 += v;
        int nf = 32 * (3 * fg + t) + (q & 3) + 8 * (q >> 2) + 4 * half;
        if (v > m) { m = v; n = nf; }
      }
    }
    float S = S0 + S1;
    float mo = __shfl_xor(m, 32);
    int   no = __shfl_xor(n, 32);
    float So = __shfl_xor(S, 32);
    bool take = (mo > m) || (mo == m && no < n);
    if (take) { m = mo; n = no; }
    S += So;
    if (half == 0) {
      int o = ((rp2 + d) * 2 + fg) * 64 + colp;
      pm[o] = m; pn[o] = n; pS[o] = S;
    }
  }
  __syncthreads();

  // stage 2: fg==0 waves combine groups, write orientation
  if (fg == 0) {
#pragma unroll
    for (int d = 0; d < 2; d++) {
      int rd = rp2 + d;
      int o0 = (rd * 2 + 0) * 64 + colp;
      int o1 = (rd * 2 + 1) * 64 + colp;
      float m0 = pm[o0], m1 = pm[o1];
      int n = (m1 > m0) ? pn[o1] : pn[o0];   // strict > keeps smaller index on tie
      float S = pS[o0] + pS[o1];
      float om = (float)n / 180.0f * 255.0f;
      if (half == 0) {
        fn[rd * 64 + colp] = n; fS[rd * 64 + colp] = S;
        out[(size_t)b * NPIX + (size_t)(y0 + rd) * W + x0 + colp] = om;
      }
    }
  }
  __syncthreads();

  // stage 3: all waves, partial confidence with the final winner
#pragma unroll
  for (int d = 0; d < 2; d++) {
    int rd = rp2 + d;
    int nwin = fn[rd * 64 + colp];
    float om = (float)nwin / 180.0f * 255.0f;
    float rad = om / 180.0f * PI_F;
    float ddc = rad - hbase;
    float C0 = 0.f, C1 = 0.f;
#pragma unroll
    for (int t = 0; t < 3; t++) {
#pragma unroll
      for (int q = 0; q < 16; q++) {
        const float K = (float)((double)(32 * (3 * fg + t) + (q & 3) + 8 * (q >> 2)) * STEPD);
        float dd = ddc - K;
        float r = rintf(dd * INV_PI);
        float dist = fmaf(-PI_F, r, dd);
        float w2 = dist * dist;
        if (q & 1) C1 = fmaf(w2, fabsf(acc[d][t][q]), C1);
        else       C0 = fmaf(w2, fabsf(acc[d][t][q]), C0);
      }
    }
    float C = C0 + C1;
    C += __shfl_xor(C, 32);
    if (half == 0) pc[(rd * 2 + fg) * 64 + colp] = C;
  }
  __syncthreads();

  // stage 4: fg==0 waves finalize confidence
  if (fg == 0) {
#pragma unroll
    for (int d = 0; d < 2; d++) {
      int rd = rp2 + d;
      float C = pc[(rd * 2 + 0) * 64 + colp] + pc[(rd * 2 + 1) * 64 + colp];
      if (half == 0) {
        out[(size_t)NB * NPIX + (size_t)b * NPIX + (size_t)(y0 + rd) * W + x0 + colp]
            = C / fS[rd * 64 + colp];
      }
    }
  }
}

extern "C" void kernel_launch(void* const* d_in, const int* in_sizes, int n_in,
                              void* d_out, int out_size, void* d_ws, size_t ws_size,
                              hipStream_t stream) {
  const float* x = (const float*)d_in[0];      // [2,3,512,512]
  const float* wts = (const float*)d_in[1];    // [180,1,17,17]
  const float* bins = (const float*)d_in[2];   // [180]
  float* out = (float*)d_out;

  float* ws = (float*)d_ws;
  float* gray = ws;                                 // 524288 f32
  float* tmpA = ws + (size_t)NB * NPIX;             // 524288 f32
  float* tmpB = tmpA + (size_t)NB * NPIX;           // 524288 f32
  uint32_t* dogp = (uint32_t*)(tmpB + (size_t)NB * NPIX);  // 524288 u32
  float* taps = (float*)(dogp + (size_t)NB * NPIX); // 128 f32
  uint32_t* Bf = (uint32_t*)(taps + 128);           // 19*3072 u32

  k_taps<<<1, 64, 0, stream>>>(taps);
  k_repackB<<<114, 256, 0, stream>>>(wts, Bf);

  int n = NB * NPIX;
  int blk = 256, grd = (n + blk - 1) / blk;
  k_gray<<<grd, blk, 0, stream>>>(x, gray);
  k_vblur2<<<grd, blk, 0, stream>>>(gray, tmpA, tmpB, taps);
  k_hblur_dog<<<grd, blk, 0, stream>>>(tmpA, tmpB, dogp, taps);

  dim3 g(W / 64, H / 4, NB);
  k_conv<<<g, 512, 0, stream>>>(dogp, Bf, bins, out);
}